// Round 11
// baseline (233.207 us; speedup 1.0000x reference)
//
#include <hip/hip_runtime.h>
#include <hip/hip_bf16.h>
#include <stdint.h>
#include <stddef.h>

typedef __bf16 bf16_t;
typedef __bf16 bf16x4 __attribute__((ext_vector_type(4)));
typedef __bf16 bf16x8 __attribute__((ext_vector_type(8)));
typedef float  f32x4  __attribute__((ext_vector_type(4)));

#define Bsz  4
#define Ssz  2048
#define Dsz  768
#define Isz  1536
#define Hn   8
#define HDsz 64
#define NTOK (Bsz*Ssz)      /* 8192 */
#define Lc   64
#define NCH  (Ssz/Lc)       /* 32 */
#define NBH  (Bsz*Hn)       /* 32 */
#define NUX  1664           /* up-proj fused N: 1536 u + 16 if + 112 pad (13 tiles) */

/* ---------------- workspace layout (bytes) ---------------- */
#define OFF_H      ((size_t)0)                    /* 12.58M; CstB aliases */
#define OFF_WUPX   ((size_t)12582912)             /* 1664x768 bf16 = 2.56M */
#define OFF_WQX    ((size_t)15138816)             /* 2048x1536 bf16 = 6.29M */
#define OFF_WDOWNT ((size_t)21430272)             /* 2.36M */
#define OFF_WOC    ((size_t)23789568)             /* 768x512 bf16 = 0.79M */
#define OFF_BIAS   ((size_t)24576000)             /* 528 f32, pad to 4K */
#define OFF_U      ((size_t)24580096)             /* 25.17M */
#define OFF_QKVO   ((size_t)49745920)             /* 8192x2048 bf16 = 33.55M */
#define OFF_KT     ((size_t)83300352)             /* 8.39M */
#define OFF_VT     ((size_t)91688960)             /* 8.39M */
#define OFF_IFB    ((size_t)100077568)            /* 0.52M */
#define OFF_BLOC   ((size_t)100601856)
#define OFF_MHAT   ((size_t)100864000)
#define OFF_MST    ((size_t)101126144)
#define OFF_DEC    ((size_t)101130240)
#define OFF_MEND   ((size_t)101134336)
#define OFF_NG     ((size_t)101138432)
#define OFF_NST    ((size_t)101400576)            /* end 101662720 */
/* aliases (all dead before their region is overwritten) */
#define OFF_CSTB   ((size_t)0)                    /* over H (dead after up-gemm) */
#define OFF_WOUTB  OFF_QKVO                       /* W_out bf16 (512x1536) */
#define OFF_WUPB   (OFF_QKVO + 1572864)           /* W_up bf16 row-major (768x1536) */
#define OFF_WIF128 (OFF_QKVO + 3932160)           /* 128x1536 bf16 (16 real + 112 zero) */
#define OFF_G      OFF_U                          /* over u (dead after qkvo-gemm) */
#define OFF_GATED  (OFF_U + 16777216)

/* ---------------- helpers ---------------- */
__device__ __forceinline__ void gload16(const void* gsrc, void* ldst) {
  __builtin_amdgcn_global_load_lds(
      (const __attribute__((address_space(1))) void*)gsrc,
      (__attribute__((address_space(3))) void*)ldst, 16, 0, 0);
}

__device__ __forceinline__ float blockReduceSum256(float v) {
  #pragma unroll
  for (int o = 1; o < 64; o <<= 1) v += __shfl_xor(v, o, 64);
  __shared__ float sh[4];
  int wid = threadIdx.x >> 6;
  __syncthreads();
  if ((threadIdx.x & 63) == 0) sh[wid] = v;
  __syncthreads();
  return sh[0] + sh[1] + sh[2] + sh[3];
}

/* ---------------- weight transpose+cast ---------------- */
__global__ __launch_bounds__(256) void transpose_cast(const float* __restrict__ W,
                                                      bf16_t* __restrict__ Wt,
                                                      int K, int N, float scale) {
  __shared__ float tile[32][33];
  int n0 = blockIdx.x * 32, k0 = blockIdx.y * 32;
  int tx = threadIdx.x, ty = threadIdx.y;
  #pragma unroll
  for (int j = 0; j < 32; j += 8)
    tile[ty + j][tx] = W[(size_t)(k0 + ty + j) * N + n0 + tx];
  __syncthreads();
  #pragma unroll
  for (int j = 0; j < 32; j += 8)
    Wt[(size_t)(n0 + ty + j) * K + k0 + tx] = (bf16_t)(tile[tx][ty + j] * scale);
}

/* ---------------- plain f32 -> bf16 cast ---------------- */
__global__ __launch_bounds__(256) void cast_bf16(const float* __restrict__ W,
                                                 bf16_t* __restrict__ Wb, int n) {
  int i = blockIdx.x * 256 + threadIdx.x;
  if (i < n) Wb[i] = (bf16_t)W[i];
}

/* ---------------- build Wif^T (16x1536) into first rows of a zeroed 128x1536 ---------------- */
__global__ __launch_bounds__(256) void build_wift(const float* __restrict__ Wi,
                                                  const float* __restrict__ Wf,
                                                  bf16_t* __restrict__ dst) {
  int idx = blockIdx.x * 256 + threadIdx.x;
  if (idx < 16 * 1536) {
    int n = idx / 1536, k = idx - n * 1536;
    float v = (n < 8) ? Wi[(size_t)k * 8 + n] : Wf[(size_t)k * 8 + (n - 8)];
    dst[idx] = (bf16_t)v;
  }
}

/* ---------------- packed bias [bo(512), bi(8), bf(8)] ---------------- */
__global__ void build_bias(const float* __restrict__ bo, const float* __restrict__ bi,
                           const float* __restrict__ bfv, float* __restrict__ out) {
  int i = blockIdx.x * 256 + threadIdx.x;
  if (i < 512) out[i] = bo[i];
  else if (i < 520) out[i] = bi[i - 512];
  else if (i < 528) out[i] = bfv[i - 520];
}

/* ---------------- LayerNorm ---------------- */
__global__ __launch_bounds__(256) void ln_kernel(const float* __restrict__ x,
                                                 const float* __restrict__ g,
                                                 const float* __restrict__ bta,
                                                 bf16_t* __restrict__ h) {
  size_t tok = blockIdx.x;
  const float* xr = x + tok * Dsz;
  int t = threadIdx.x;
  float v[3]; float s = 0.f;
  #pragma unroll
  for (int i = 0; i < 3; ++i) { v[i] = xr[t + 256 * i]; s += v[i]; }
  s = blockReduceSum256(s);
  float mu = s * (1.f / Dsz);
  float s2 = 0.f;
  #pragma unroll
  for (int i = 0; i < 3; ++i) { float d = v[i] - mu; s2 += d * d; }
  s2 = blockReduceSum256(s2);
  float rs = rsqrtf(s2 * (1.f / Dsz) + 1e-5f);
  #pragma unroll
  for (int i = 0; i < 3; ++i) {
    int col = t + 256 * i;
    h[tok * Dsz + col] = (bf16_t)((v[i] - mu) * rs * g[col] + bta[col]);
  }
}

/* ======================================================================
   256M x 128N m97-style GEMM (proven config: launch_bounds(512,4), VGPR 60).
   EPI: 0 = bf16 out; 3 = f32 out + resid;
        5 = qkvo epilogue (N=2048, grid 512 = exactly 2 blocks/CU):
            col<512   q  -> qkvo
            col<1024  k  -> qkvo + kTg (transposed)
            col<1536  v  -> vTg only
            col<2048  o  -> qkvo = sigmoid(acc + bias[col-1536])
        6 = up+if epilogue (N must be NUX=1664, u stride 1536):
            col<1536  u  -> bf16
            col<1552  if -> ifb f32 = acc + bias[col-1536] (extra = biasA+512)
            else discard (weight rows zeroed)
   ====================================================================== */
template<int EPI>
__global__ __launch_bounds__(512, 4) void gemm_mn(const bf16_t* __restrict__ A,
                                                  const bf16_t* __restrict__ Bt,
                                                  void* __restrict__ Cout,
                                                  const void* __restrict__ extra,
                                                  bf16_t* __restrict__ kTg,
                                                  bf16_t* __restrict__ vTg,
                                                  float* __restrict__ ifb,
                                                  int M, int N, int K) {
  __shared__ bf16_t As[256 * 64];
  __shared__ bf16_t Bs[128 * 64];
  const int t = threadIdx.x;
  const int w = t >> 6, l = t & 63;
  const int wm = w >> 1, wn = w & 1;
  const int l15 = l & 15, l4 = l >> 4;

  /* bijective XCD swizzle (nwg % 8 == 0 for all launches) */
  const int gx = gridDim.x;
  const int nwg = gx * gridDim.y;
  const int cpx = nwg >> 3;
  int bid = blockIdx.y * gx + blockIdx.x;
  int wg = (bid & 7) * cpx + (bid >> 3);
  const int tile_m = (wg / gx) * 256;
  const int tile_n = (wg % gx) * 128;

  f32x4 acc[4][4];
  #pragma unroll
  for (int m = 0; m < 4; ++m)
    #pragma unroll
    for (int n = 0; n < 4; ++n) acc[m][n] = (f32x4){0.f, 0.f, 0.f, 0.f};

  for (int k0 = 0; k0 < K; k0 += 64) {
    #pragma unroll
    for (int j = 0; j < 4; ++j) {
      int c = t + j * 512;
      int row = c >> 3;
      int ec = ((c & 7) * 8) ^ ((row & 7) << 3);
      gload16(A + (size_t)(tile_m + row) * K + k0 + ec, (char*)As + (size_t)c * 16);
    }
    #pragma unroll
    for (int j = 0; j < 2; ++j) {
      int c = t + j * 512;
      int row = c >> 3;
      int ec = ((c & 7) * 8) ^ ((row & 7) << 3);
      gload16(Bt + (size_t)(tile_n + row) * K + k0 + ec, (char*)Bs + (size_t)c * 16);
    }
    __syncthreads();
    #pragma unroll
    for (int kk = 0; kk < 2; ++kk) {
      bf16x8 aF[4], bF[4];
      #pragma unroll
      for (int m = 0; m < 4; ++m) {
        int r = wm * 64 + m * 16 + l15;
        aF[m] = *(const bf16x8*)((const char*)As + r * 128 + ((kk * 64 + l4 * 16) ^ ((r & 7) << 4)));
      }
      #pragma unroll
      for (int n = 0; n < 4; ++n) {
        int r = wn * 64 + n * 16 + l15;
        bF[n] = *(const bf16x8*)((const char*)Bs + r * 128 + ((kk * 64 + l4 * 16) ^ ((r & 7) << 4)));
      }
      #pragma unroll
      for (int m = 0; m < 4; ++m)
        #pragma unroll
        for (int n = 0; n < 4; ++n)
          acc[m][n] = __builtin_amdgcn_mfma_f32_16x16x32_bf16(aF[m], bF[n], acc[m][n], 0, 0, 0);
    }
    __syncthreads();
  }

  const int rbase = tile_m + wm * 64 + l4 * 4;
  const int cbase = tile_n + wn * 64 + l15;
  if constexpr (EPI == 5) {
    const float* bias = (const float*)extra;
    #pragma unroll
    for (int m = 0; m < 4; ++m) {
      int row0 = rbase + m * 16;             /* rows row0..row0+3, mult of 4 */
      int bb = row0 >> 11, s0 = row0 & 2047;
      #pragma unroll
      for (int n = 0; n < 4; ++n) {
        int col = cbase + n * 16;
        if (col < 512) {
          #pragma unroll
          for (int j = 0; j < 4; ++j)
            ((bf16_t*)Cout)[(size_t)(row0 + j) * 2048 + col] = (bf16_t)acc[m][n][j];
        } else if (col < 1024) {
          int hd = col - 512;
          bf16x4 pk;
          #pragma unroll
          for (int j = 0; j < 4; ++j) {
            bf16_t bv = (bf16_t)acc[m][n][j];
            ((bf16_t*)Cout)[(size_t)(row0 + j) * 2048 + col] = bv;
            pk[j] = bv;
          }
          *(bf16x4*)(kTg + ((size_t)(bb * 8 + (hd >> 6)) * 64 + (hd & 63)) * Ssz + s0) = pk;
        } else if (col < 1536) {
          int hd = col - 1024;
          bf16x4 pv;
          #pragma unroll
          for (int j = 0; j < 4; ++j) pv[j] = (bf16_t)acc[m][n][j];
          *(bf16x4*)(vTg + ((size_t)(bb * 8 + (hd >> 6)) * 64 + (hd & 63)) * Ssz + s0) = pv;
        } else {
          float b = bias[col - 1536];
          #pragma unroll
          for (int j = 0; j < 4; ++j) {
            float z = acc[m][n][j] + b;
            ((bf16_t*)Cout)[(size_t)(row0 + j) * 2048 + col] = (bf16_t)(1.f / (1.f + __expf(-z)));
          }
        }
      }
    }
  } else if constexpr (EPI == 6) {
    const float* bias = (const float*)extra;   /* biasA+512: [bi(8), bf(8)] */
    #pragma unroll
    for (int m = 0; m < 4; ++m)
      #pragma unroll
      for (int n = 0; n < 4; ++n) {
        int col = cbase + n * 16;
        if (col < 1536) {
          #pragma unroll
          for (int j = 0; j < 4; ++j)
            ((bf16_t*)Cout)[(size_t)(rbase + m * 16 + j) * 1536 + col] = (bf16_t)acc[m][n][j];
        } else if (col < 1552) {
          float b = bias[col - 1536];
          #pragma unroll
          for (int j = 0; j < 4; ++j)
            ifb[(size_t)(rbase + m * 16 + j) * 16 + (col - 1536)] = acc[m][n][j] + b;
        }
      }
  } else {
    #pragma unroll
    for (int m = 0; m < 4; ++m)
      #pragma unroll
      for (int n = 0; n < 4; ++n)
        #pragma unroll
        for (int j = 0; j < 4; ++j) {
          int row = rbase + m * 16 + j;
          int col = cbase + n * 16;
          float v = acc[m][n][j];
          if constexpr (EPI == 0) {
            ((bf16_t*)Cout)[(size_t)row * N + col] = (bf16_t)v;
          } else {  /* EPI == 3 */
            ((float*)Cout)[(size_t)row * N + col] =
                v + ((const float*)extra)[(size_t)row * N + col];
          }
        }
  }
}

/* ---------------- 128^2 MFMA GEMM (weight precompute: Woc, Wuif) ---------------- */
__global__ __launch_bounds__(256) void gemm_bt(const bf16_t* __restrict__ A,
                                               const bf16_t* __restrict__ Bt,
                                               bf16_t* __restrict__ Cout,
                                               int M, int N, int K) {
  __shared__ bf16_t As[128 * 64];
  __shared__ bf16_t Bs[128 * 64];
  const int t = threadIdx.x;
  const int w = t >> 6, l = t & 63;
  const int tile_m = blockIdx.y * 128, tile_n = blockIdx.x * 128;
  const int wr = w >> 1, wc = w & 1;
  const int lrow = l >> 3;
  const int lks = ((l & 7) * 8) ^ (lrow << 3);
  const int l15 = l & 15, l4 = l >> 4;

  f32x4 acc[4][4];
  #pragma unroll
  for (int m = 0; m < 4; ++m)
    #pragma unroll
    for (int n = 0; n < 4; ++n) acc[m][n] = (f32x4){0.f, 0.f, 0.f, 0.f};

  for (int k0 = 0; k0 < K; k0 += 64) {
    #pragma unroll
    for (int i = 0; i < 4; ++i) {
      int ch = w * 4 + i;
      int row = ch * 8 + lrow;
      gload16(A  + (size_t)(tile_m + row) * K + k0 + lks, &As[ch * 512]);
      gload16(Bt + (size_t)(tile_n + row) * K + k0 + lks, &Bs[ch * 512]);
    }
    __syncthreads();
    #pragma unroll
    for (int kk = 0; kk < 2; ++kk) {
      bf16x8 af[4], bfr[4];
      #pragma unroll
      for (int m = 0; m < 4; ++m) {
        int r = wr * 64 + m * 16 + l15;
        af[m] = *(const bf16x8*)&As[r * 64 + ((kk * 32 + l4 * 8) ^ ((r & 7) << 3))];
      }
      #pragma unroll
      for (int n = 0; n < 4; ++n) {
        int r = wc * 64 + n * 16 + l15;
        bfr[n] = *(const bf16x8*)&Bs[r * 64 + ((kk * 32 + l4 * 8) ^ ((r & 7) << 3))];
      }
      #pragma unroll
      for (int m = 0; m < 4; ++m)
        #pragma unroll
        for (int n = 0; n < 4; ++n)
          acc[m][n] = __builtin_amdgcn_mfma_f32_16x16x32_bf16(af[m], bfr[n], acc[m][n], 0, 0, 0);
    }
    __syncthreads();
  }

  const int rbase = tile_m + wr * 64 + l4 * 4;
  const int cbase = tile_n + wc * 64 + l15;
  #pragma unroll
  for (int m = 0; m < 4; ++m)
    #pragma unroll
    for (int n = 0; n < 4; ++n)
      #pragma unroll
      for (int j = 0; j < 4; ++j)
        Cout[(size_t)(rbase + m * 16 + j) * N + cbase + n * 16] = (bf16_t)acc[m][n][j];
}

/* ---------------- gates pass A ---------------- */
__global__ __launch_bounds__(64) void gates_a(const float* __restrict__ ifb,
                                              float* __restrict__ blocal,
                                              float* __restrict__ Mhat) {
  int bh = blockIdx.x >> 5, c = blockIdx.x & 31;
  int b = bh >> 3, h = bh & 7;
  int lane = threadIdx.x;
  size_t tok = (size_t)b * Ssz + c * Lc + lane;
  float iv = ifb[tok * 16 + h];
  float fv = ifb[tok * 16 + 8 + h];
  float bt = fv;
  #pragma unroll
  for (int d = 1; d < 64; d <<= 1) { float o = __shfl_up(bt, d, 64); if (lane >= d) bt += o; }
  float a = iv - bt;
  float pm = a;
  #pragma unroll
  for (int d = 1; d < 64; d <<= 1) { float o = __shfl_up(pm, d, 64); if (lane >= d) pm = fmaxf(pm, o); }
  blocal[(size_t)bh * Ssz + c * Lc + lane] = bt;
  Mhat[(size_t)bh * Ssz + c * Lc + lane] = bt + pm;
}

/* ---------------- gates pass B ---------------- */
__global__ void gates_b(const float* __restrict__ blocal, const float* __restrict__ Mhat,
                        float* __restrict__ mstart, float* __restrict__ decays,
                        float* __restrict__ mend) {
  int bh = threadIdx.x;
  if (bh < NBH) {
    float M = 0.f;
    for (int c = 0; c < NCH; ++c) {
      mstart[bh * NCH + c] = M;
      float bL = blocal[(size_t)bh * Ssz + c * Lc + 63];
      float Mh = Mhat[(size_t)bh * Ssz + c * Lc + 63];
      float Mn = fmaxf(M + bL, Mh);
      decays[bh * NCH + c] = __expf(M + bL - Mn);
      mend[bh * NCH + c] = Mn;
      M = Mn;
    }
  }
}

/* ---------------- per-chunk state increment, MFMA ---------------- */
__global__ __launch_bounds__(256) void chunk_inc_mfma(const bf16_t* __restrict__ kTg,
                                                      const bf16_t* __restrict__ vTg,
                                                      const float* __restrict__ ifb,
                                                      const float* __restrict__ blocal,
                                                      const float* __restrict__ mend,
                                                      bf16_t* __restrict__ G,
                                                      float* __restrict__ ng) {
  int bh = blockIdx.x >> 5, c = blockIdx.x & 31;
  int b = bh >> 3, h = bh & 7;
  __shared__ bf16_t Vt[64 * 64];
  __shared__ bf16_t Kw[64 * 64];
  __shared__ float wsh[64];
  const int t = threadIdx.x, w = t >> 6, l = t & 63;
  const int l15 = l & 15, l4 = l >> 4;
  if (t < 64) {
    float mL = mend[bh * NCH + c];
    float bL = blocal[(size_t)bh * Ssz + c * Lc + 63];
    float bt = blocal[(size_t)bh * Ssz + c * Lc + t];
    float iv = ifb[((size_t)b * Ssz + c * Lc + t) * 16 + h];
    wsh[t] = __expf(iv + bL - bt - mL);
  }
  __syncthreads();
  {
    const int r = l >> 3, c8 = (l & 7) * 8;
    #pragma unroll
    for (int i = 0; i < 2; ++i) {
      int seg = w * 2 + i, row = seg * 8 + r;
      gload16(vTg + ((size_t)bh * 64 + row) * Ssz + c * 64 + c8, &Vt[seg * 512]);
    }
    #pragma unroll
    for (int i = 0; i < 2; ++i) {
      int e = t + i * 256; int row = e >> 3, c0 = (e & 7) * 8;
      bf16x8 kv = *(const bf16x8*)(kTg + ((size_t)bh * 64 + row) * Ssz + c * 64 + c0);
      #pragma unroll
      for (int j = 0; j < 8; ++j) kv[j] = (bf16_t)((float)kv[j] * wsh[c0 + j]);
      *(bf16x8*)&Kw[row * 64 + c0] = kv;
    }
  }
  __syncthreads();
  f32x4 acc[4];
  #pragma unroll
  for (int n = 0; n < 4; ++n) acc[n] = (f32x4){0.f, 0.f, 0.f, 0.f};
  #pragma unroll
  for (int kk = 0; kk < 2; ++kk) {
    bf16x8 af = *(const bf16x8*)&Vt[(w * 16 + l15) * 64 + kk * 32 + l4 * 8];
    #pragma unroll
    for (int n = 0; n < 4; ++n) {
      bf16x8 bfr = *(const bf16x8*)&Kw[(n * 16 + l15) * 64 + kk * 32 + l4 * 8];
      acc[n] = __builtin_amdgcn_mfma_f32_16x16x32_bf16(af, bfr, acc[n], 0, 0, 0);
    }
  }
  size_t gb = ((size_t)bh * NCH + c) * 4096;
  #pragma unroll
  for (int n = 0; n < 4; ++n)
    #pragma unroll
    for (int j = 0; j < 4; ++j) {
      int row = w * 16 + l4 * 4 + j;
      int col = n * 16 + l15;
      G[gb + (size_t)row * 64 + col] = (bf16_t)acc[n][j];
    }
  if (t < 64) {
    float s = 0.f;
    for (int s2 = 0; s2 < 64; ++s2) s += (float)Kw[t * 64 + s2];
    ng[((size_t)bh * NCH + c) * 64 + t] = s;
  }
}

/* ---------------- state scan ---------------- */
__global__ __launch_bounds__(256) void state_scan(const bf16_t* __restrict__ G,
                                                  const float* __restrict__ ng,
                                                  const float* __restrict__ decays,
                                                  bf16_t* __restrict__ CstB,
                                                  float* __restrict__ nst) {
  int gid = blockIdx.x;
  if (gid < 512) {
    int idx = gid * 256 + threadIdx.x;
    int bh = idx >> 12, e = idx & 4095;
    const float* d = decays + bh * NCH;
    float C = 0.f;
    #pragma unroll
    for (int c = 0; c < NCH; ++c) {
      size_t o = ((size_t)bh * NCH + c) * 4096 + e;
      CstB[o] = (bf16_t)C;
      C = d[c] * C + (float)G[o];
    }
  } else {
    int idx = (gid - 512) * 256 + threadIdx.x;
    int bh = idx >> 6, e = idx & 63;
    const float* d = decays + bh * NCH;
    float n = 0.f;
    #pragma unroll
    for (int c = 0; c < NCH; ++c) {
      size_t o = ((size_t)bh * NCH + c) * 64 + e;
      nst[o] = n;
      n = d[c] * n + ng[o];
    }
  }
}

/* ---------------- intra-chunk outputs + fused group-norm/out-gate ---------------- */
__global__ __launch_bounds__(256) void intra_mfma(const bf16_t* __restrict__ qkvo,
                                                  const bf16_t* __restrict__ vTg,
                                                  const bf16_t* __restrict__ CstB,
                                                  const float* __restrict__ nst,
                                                  const float* __restrict__ ifb,
                                                  const float* __restrict__ blocal,
                                                  const float* __restrict__ Mhat,
                                                  const float* __restrict__ mstart,
                                                  const float* __restrict__ mhg,
                                                  bf16_t* __restrict__ gated) {
  int bh = blockIdx.x >> 5, c = blockIdx.x & 31;
  int b = bh >> 3, h = bh & 7;
  __shared__ bf16_t qs[64 * 64];
  __shared__ bf16_t ks[64 * 64];
  __shared__ bf16_t vTs[64 * 64];
  __shared__ bf16_t Cs[64 * 64];
  __shared__ float nin[64], den_s[64], ssrc[64], sdst[64], esc[64];
  const int t = threadIdx.x, w = t >> 6, l = t & 63;
  const int l15 = l & 15, l4 = l >> 4;
  const size_t tok0 = (size_t)b * Ssz + c * Lc;
  const size_t cbase = ((size_t)bh * NCH + c) * 4096;

  if (t < 64) {
    nin[t] = nst[((size_t)bh * NCH + c) * 64 + t];
    float bt = blocal[(size_t)bh * Ssz + c * Lc + t];
    float Mh2 = Mhat[(size_t)bh * Ssz + c * Lc + t];
    float Mc = mstart[bh * NCH + c];
    float iv = ifb[(tok0 + t) * 16 + h];
    float mt = fmaxf(Mc + bt, Mh2);
    ssrc[t] = iv - bt;
    sdst[t] = bt - mt;
    esc[t]  = __expf(Mc + bt - mt);
  }
  {
    const int r = l >> 3, c8 = (l & 7) * 8;
    #pragma unroll
    for (int i = 0; i < 2; ++i) {
      int seg = w * 2 + i, row = seg * 8 + r;
      gload16(qkvo + (tok0 + row) * 2048 + h * 64 + c8,          &qs[seg * 512]);
      gload16(qkvo + (tok0 + row) * 2048 + 512 + h * 64 + c8,    &ks[seg * 512]);
      gload16(vTg + ((size_t)bh * 64 + row) * Ssz + c * 64 + c8, &vTs[seg * 512]);
      gload16(CstB + cbase + seg * 512 + l * 8,                  &Cs[seg * 512]);
    }
  }
  __syncthreads();

  f32x4 aS[4];
  #pragma unroll
  for (int n = 0; n < 4; ++n) aS[n] = (f32x4){0.f, 0.f, 0.f, 0.f};
  #pragma unroll
  for (int kk = 0; kk < 2; ++kk) {
    bf16x8 af = *(const bf16x8*)&qs[(w * 16 + l15) * 64 + kk * 32 + l4 * 8];
    #pragma unroll
    for (int n = 0; n < 4; ++n) {
      bf16x8 bfr = *(const bf16x8*)&ks[(n * 16 + l15) * 64 + kk * 32 + l4 * 8];
      aS[n] = __builtin_amdgcn_mfma_f32_16x16x32_bf16(af, bfr, aS[n], 0, 0, 0);
    }
  }
  {
    int row = w * 16 + (l >> 2);
    int c0 = (l & 3) * 16;
    float e = esc[row];
    #pragma unroll
    for (int i2 = 0; i2 < 2; ++i2) {
      bf16x8 v8 = *(const bf16x8*)&qs[row * 64 + c0 + i2 * 8];
      #pragma unroll
      for (int j = 0; j < 8; ++j) v8[j] = (bf16_t)((float)v8[j] * e);
      *(bf16x8*)&qs[row * 64 + c0 + i2 * 8] = v8;
    }
  }
  float rs[4] = {0.f, 0.f, 0.f, 0.f};
  #pragma unroll
  for (int n = 0; n < 4; ++n) {
    int col = n * 16 + l15;
    float es = ssrc[col];
    #pragma unroll
    for (int j = 0; j < 4; ++j) {
      int row = w * 16 + l4 * 4 + j;
      float p = (col <= row) ? aS[n][j] * __expf(es + sdst[row]) : 0.f;
      aS[n][j] = p;
      rs[j] += p;
    }
  }
  #pragma unroll
  for (int j = 0; j < 4; ++j) {
    rs[j] += __shfl_xor(rs[j], 1, 64);
    rs[j] += __shfl_xor(rs[j], 2, 64);
    rs[j] += __shfl_xor(rs[j], 4, 64);
    rs[j] += __shfl_xor(rs[j], 8, 64);
  }
  if (l15 == 0) {
    #pragma unroll
    for (int j = 0; j < 4; ++j) den_s[w * 16 + l4 * 4 + j] = rs[j];
  }
  __syncthreads();

  #pragma unroll
  for (int n = 0; n < 4; ++n)
    #pragma unroll
    for (int j = 0; j < 4; ++j)
      ks[(w * 16 + l4 * 4 + j) * 64 + n * 16 + l15] = (bf16_t)aS[n][j];

  {
    int row = w * 16 + (l >> 2);
    int c0 = (l & 3) * 16;
    float part = 0.f;
    #pragma unroll
    for (int i2 = 0; i2 < 16; ++i2)
      part += (float)qs[row * 64 + c0 + i2] * nin[c0 + i2];
    part += __shfl_xor(part, 1, 64);
    part += __shfl_xor(part, 2, 64);
    if ((l & 3) == 0)
      den_s[row] = fmaxf(fabsf(den_s[row] + part), 1.0f);
  }
  __syncthreads();

  f32x4 aO[4];
  #pragma unroll
  for (int n = 0; n < 4; ++n) aO[n] = (f32x4){0.f, 0.f, 0.f, 0.f};
  #pragma unroll
  for (int kk = 0; kk < 2; ++kk) {
    bf16x8 afP = *(const bf16x8*)&ks[(w * 16 + l15) * 64 + kk * 32 + l4 * 8];
    bf16x8 afQ = *(const bf16x8*)&qs[(w * 16 + l15) * 64 + kk * 32 + l4 * 8];
    #pragma unroll
    for (int n = 0; n < 4; ++n) {
      bf16x8 bV = *(const bf16x8*)&vTs[(n * 16 + l15) * 64 + kk * 32 + l4 * 8];
      bf16x8 bC = *(const bf16x8*)&Cs[(n * 16 + l15) * 64 + kk * 32 + l4 * 8];
      aO[n] = __builtin_amdgcn_mfma_f32_16x16x32_bf16(afP, bV, aO[n], 0, 0, 0);
      aO[n] = __builtin_amdgcn_mfma_f32_16x16x32_bf16(afQ, bC, aO[n], 0, 0, 0);
    }
  }

  /* fused per-row group-norm (64 cols in 16 lanes x 4 regs) + sigmoid(og)*mh_g */
  #pragma unroll
  for (int j = 0; j < 4; ++j) {
    int row = w * 16 + l4 * 4 + j;
    float rinv = 1.f / den_s[row];
    float ov[4];
    #pragma unroll
    for (int n = 0; n < 4; ++n) ov[n] = aO[n][j] * rinv;
    float s = ov[0] + ov[1] + ov[2] + ov[3];
    s += __shfl_xor(s, 1, 64); s += __shfl_xor(s, 2, 64);
    s += __shfl_xor(s, 4, 64); s += __shfl_xor(s, 8, 64);
    float mu = s * (1.f / 64.f);
    float s2 = 0.f;
    #pragma unroll
    for (int n = 0; n < 4; ++n) { float d = ov[n] - mu; s2 += d * d; }
    s2 += __shfl_xor(s2, 1, 64); s2 += __shfl_xor(s2, 2, 64);
    s2 += __shfl_xor(s2, 4, 64); s2 += __shfl_xor(s2, 8, 64);
    float rstd = rsqrtf(s2 * (1.f / 64.f) + 1e-5f);
    size_t tok = tok0 + row;
    #pragma unroll
    for (int n = 0; n < 4; ++n) {
      int colh = n * 16 + l15;
      float og = (float)qkvo[tok * 2048 + 1536 + h * 64 + colh];
      float hn = (ov[n] - mu) * rstd * mhg[h * 64 + colh];
      gated[tok * 512 + h * 64 + colh] = (bf16_t)(og * hn);
    }
  }
}

/* ---------------- launcher ---------------- */
extern "C" void kernel_launch(void* const* d_in, const int* in_sizes, int n_in,
                              void* d_out, int out_size, void* d_ws, size_t ws_size,
                              hipStream_t stream) {
  const float* x     = (const float*)d_in[0];
  const float* ln_g  = (const float*)d_in[1];
  const float* ln_b  = (const float*)d_in[2];
  const float* W_up  = (const float*)d_in[3];
  const float* W_down= (const float*)d_in[4];
  const float* Wq    = (const float*)d_in[5];
  const float* Wk    = (const float*)d_in[6];
  const float* Wv    = (const float*)d_in[7];
  const float* Wi    = (const float*)d_in[8];
  const float* bi    = (const float*)d_in[9];
  const float* Wf    = (const float*)d_in[10];
  const float* bfv   = (const float*)d_in[11];
  const float* Wo    = (const float*)d_in[12];
  const float* bo    = (const float*)d_in[13];
  const float* mh_g  = (const float*)d_in[14];
  const float* W_out = (const float*)d_in[15];

  char* ws = (char*)d_ws;
  bf16_t* hbuf   = (bf16_t*)(ws + OFF_H);
  bf16_t* wupxT  = (bf16_t*)(ws + OFF_WUPX);
  bf16_t* wqxT   = (bf16_t*)(ws + OFF_WQX);
  bf16_t* wdownT = (bf16_t*)(ws + OFF_WDOWNT);
  bf16_t* wocT   = (bf16_t*)(ws + OFF_WOC);
  float*  biasA  = (float*)(ws + OFF_BIAS);
  bf16_t* ubuf   = (bf16_t*)(ws + OFF_U);
  bf16_t* qkvob  = (bf16_t*)(ws + OFF_QKVO);
  bf16_t* woutB  = (bf16_t*)(ws + OFF_WOUTB);
  bf16_t* wupB   = (bf16_t*)(ws + OFF_WUPB);
  bf16_t* wif128 = (bf16_t*)(ws + OFF_WIF128);
  bf16_t* kTg    = (bf16_t*)(ws + OFF_KT);
  bf16_t* vTg    = (bf16_t*)(ws + OFF_VT);
  float*  ifb    = (float*)(ws + OFF_IFB);
  float*  bloc   = (float*)(ws + OFF_BLOC);
  float*  Mh     = (float*)(ws + OFF_MHAT);
  float*  mst    = (float*)(ws + OFF_MST);
  float*  decays = (float*)(ws + OFF_DEC);
  float*  mendb  = (float*)(ws + OFF_MEND);
  float*  ngbuf  = (float*)(ws + OFF_NG);
  float*  nst    = (float*)(ws + OFF_NST);
  bf16_t* CstB   = (bf16_t*)(ws + OFF_CSTB);
  bf16_t* Gbuf   = (bf16_t*)(ws + OFF_G);
  bf16_t* gbuf   = (bf16_t*)(ws + OFF_GATED);

  dim3 tb(32, 8);
  transpose_cast<<<dim3(Isz / 32, Dsz / 32), tb, 0, stream>>>(W_up, wupxT, Dsz, Isz, 1.f);
  transpose_cast<<<dim3(512 / 32, Isz / 32), tb, 0, stream>>>(Wq, wqxT,                    Isz, 512, 1.f);
  transpose_cast<<<dim3(512 / 32, Isz / 32), tb, 0, stream>>>(Wk, wqxT + (size_t)512*Isz,  Isz, 512, 0.125f);
  transpose_cast<<<dim3(512 / 32, Isz / 32), tb, 0, stream>>>(Wv, wqxT + (size_t)1024*Isz, Isz, 512, 1.f);
  transpose_cast<<<dim3(512 / 32, Isz / 32), tb, 0, stream>>>(Wo, wqxT + (size_t)1536*Isz, Isz, 512, 1.f);
  transpose_cast<<<dim3(Dsz / 32, Isz / 32), tb, 0, stream>>>(W_down, wdownT, Isz, Dsz, 1.f);
  cast_bf16<<<(512 * 1536 + 255) / 256, 256, 0, stream>>>(W_out, woutB, 512 * 1536);
  cast_bf16<<<(768 * 1536 + 255) / 256, 256, 0, stream>>>(W_up, wupB, 768 * 1536);
  hipMemsetAsync(wif128, 0, (size_t)128 * 1536 * sizeof(bf16_t), stream);
  build_wift<<<96, 256, 0, stream>>>(Wi, Wf, wif128);
  build_bias<<<3, 256, 0, stream>>>(bo, bi, bfv, biasA);

  /* WocT(768,512) = wdownT @ woutB^T == (W_out @ W_down)^T */
  gemm_bt<<<dim3(512 / 128, Dsz / 128), 256, 0, stream>>>(wdownT, woutB, wocT, Dsz, 512, Isz);
  /* Wuif^T (16x768, rows 16-127 zero) = wif128 @ wupB^T -> wupxT rows 1536..1663 */
  gemm_bt<<<dim3(Dsz / 128, 1), 256, 0, stream>>>(wif128, wupB, wupxT + (size_t)1536 * Dsz, 128, Dsz, Isz);

  ln_kernel<<<NTOK, 256, 0, stream>>>(x, ln_g, ln_b, hbuf);

  /* fused up-proj + i/f-gate projection (composite weight), grid 416 */
  gemm_mn<6><<<dim3(NUX / 128, NTOK / 256), 512, 0, stream>>>(hbuf, wupxT, ubuf, biasA + 512, nullptr, nullptr, ifb, NTOK, NUX, Dsz);
  /* fused qkvo + kv-transpose + sigmoid(o), grid 512 = exactly 2 blocks/CU */
  gemm_mn<5><<<dim3(2048 / 128, NTOK / 256), 512, 0, stream>>>(ubuf, wqxT, qkvob, biasA, kTg, vTg, nullptr, NTOK, 2048, Isz);

  gates_a<<<NBH * NCH, 64, 0, stream>>>(ifb, bloc, Mh);
  gates_b<<<1, 32, 0, stream>>>(bloc, Mh, mst, decays, mendb);
  chunk_inc_mfma<<<NBH * NCH, 256, 0, stream>>>(kTg, vTg, ifb, bloc, mendb, Gbuf, ngbuf);
  state_scan<<<520, 256, 0, stream>>>(Gbuf, ngbuf, decays, CstB, nst);
  intra_mfma<<<NBH * NCH, 256, 0, stream>>>(qkvob, vTg, CstB, nst, ifb, bloc, Mh, mst, mh_g, gbuf);

  /* fused: out = x + gated @ (W_out @ W_down), K=512 */
  gemm_mn<3><<<dim3(Dsz / 128, NTOK / 256), 512, 0, stream>>>(gbuf, wocT, (float*)d_out, x, nullptr, nullptr, nullptr, NTOK, Dsz, 512);
}

// Round 12
// 175.093 us; speedup vs baseline: 1.3319x; 1.3319x over previous
//
#include <hip/hip_runtime.h>
#include <hip/hip_bf16.h>
#include <stdint.h>
#include <stddef.h>

typedef __bf16 bf16_t;
typedef __bf16 bf16x4 __attribute__((ext_vector_type(4)));
typedef __bf16 bf16x8 __attribute__((ext_vector_type(8)));
typedef float  f32x4  __attribute__((ext_vector_type(4)));

#define Bsz  4
#define Ssz  2048
#define Dsz  768
#define Isz  1536
#define Hn   8
#define HDsz 64
#define NTOK (Bsz*Ssz)      /* 8192 */
#define Lc   64
#define NCH  (Ssz/Lc)       /* 32 */
#define NBH  (Bsz*Hn)       /* 32 */
#define NUX  1664           /* up-proj fused N: 1536 u + 16 if + 112 pad (13 tiles) */

/* ---------------- workspace layout (bytes) ---------------- */
#define OFF_H      ((size_t)0)                    /* 12.58M; wocP & CstB alias */
#define OFF_WUPX   ((size_t)12582912)             /* 1664x768 bf16 = 2.56M */
#define OFF_WQX    ((size_t)15138816)             /* 2048x1536 bf16 = 6.29M */
#define OFF_WDOWNT ((size_t)21430272)             /* 2.36M */
#define OFF_WOC    ((size_t)23789568)             /* 768x512 bf16 = 0.79M */
#define OFF_BIAS   ((size_t)24576000)             /* 528 f32, pad to 4K */
#define OFF_U      ((size_t)24580096)             /* 25.17M */
#define OFF_QKVO   ((size_t)49745920)             /* 8192x2048 bf16 = 33.55M */
#define OFF_KT     ((size_t)83300352)             /* 8.39M */
#define OFF_VT     ((size_t)91688960)             /* 8.39M */
#define OFF_IFB    ((size_t)100077568)            /* 0.52M */
#define OFF_BLOC   ((size_t)100601856)
#define OFF_MHAT   ((size_t)100864000)
#define OFF_MST    ((size_t)101126144)
#define OFF_DEC    ((size_t)101130240)
#define OFF_MEND   ((size_t)101134336)
#define OFF_NG     ((size_t)101138432)
#define OFF_NST    ((size_t)101400576)            /* end 101662720 */
/* aliases (all dead before their region is overwritten) */
#define OFF_WOCP   ((size_t)0)                    /* 8x768x512 f32 = 12.58M, dead before ln writes hbuf */
#define OFF_CSTB   ((size_t)0)                    /* over H (dead after up-gemm) */
#define OFF_WOUTB  OFF_QKVO                       /* W_out bf16 (512x1536), dead before qkvo write */
#define OFF_G      OFF_U                          /* over u (dead after qkvo-gemm) */
#define OFF_GATED  (OFF_U + 16777216)

/* ---------------- helpers ---------------- */
__device__ __forceinline__ void gload16(const void* gsrc, void* ldst) {
  __builtin_amdgcn_global_load_lds(
      (const __attribute__((address_space(1))) void*)gsrc,
      (__attribute__((address_space(3))) void*)ldst, 16, 0, 0);
}

__device__ __forceinline__ float blockReduceSum256(float v) {
  #pragma unroll
  for (int o = 1; o < 64; o <<= 1) v += __shfl_xor(v, o, 64);
  __shared__ float sh[4];
  int wid = threadIdx.x >> 6;
  __syncthreads();
  if ((threadIdx.x & 63) == 0) sh[wid] = v;
  __syncthreads();
  return sh[0] + sh[1] + sh[2] + sh[3];
}

/* ======================================================================
   prep_weights — ALL weight transposes/casts/bias in ONE kernel.
   block (32,8); grid 6145:
     [0,1152)     W_up   (768,1536)  -> wupxT (transpose)
     [1152,1920)  Wq     (1536,512)  -> wqxT
     [1920,2688)  Wk  *0.125         -> wqxT + 512*Isz
     [2688,3456)  Wv                 -> wqxT + 1024*Isz
     [3456,4224)  Wo                 -> wqxT + 1536*Isz
     [4224,5376)  W_down (1536,768)  -> wdownT
     [5376,6144)  W_out cast f32->bf16 row-major (woutB)
     [6144]       bias pack [bo, bi, bf]
   ====================================================================== */
__global__ __launch_bounds__(256) void prep_weights(
    const float* __restrict__ W_up, const float* __restrict__ Wq,
    const float* __restrict__ Wk, const float* __restrict__ Wv,
    const float* __restrict__ Wo, const float* __restrict__ W_down,
    const float* __restrict__ W_out, const float* __restrict__ bo,
    const float* __restrict__ bi, const float* __restrict__ bfv,
    bf16_t* __restrict__ wupxT, bf16_t* __restrict__ wqxT,
    bf16_t* __restrict__ wdownT, bf16_t* __restrict__ woutB,
    float* __restrict__ biasA) {
  __shared__ float tile[32][33];
  const int bid = blockIdx.x;
  const int tx = threadIdx.x, ty = threadIdx.y;
  const float* src; bf16_t* dst; int K, N, bx, by; float scale = 1.f;
  if (bid < 1152)      { int l = bid;        src = W_up;   dst = wupxT;                       K = 768;  N = 1536; bx = l % 48; by = l / 48; }
  else if (bid < 1920) { int l = bid - 1152; src = Wq;     dst = wqxT;                        K = 1536; N = 512;  bx = l % 16; by = l / 16; }
  else if (bid < 2688) { int l = bid - 1920; src = Wk;     dst = wqxT + (size_t)512 * Isz;    K = 1536; N = 512;  bx = l % 16; by = l / 16; scale = 0.125f; }
  else if (bid < 3456) { int l = bid - 2688; src = Wv;     dst = wqxT + (size_t)1024 * Isz;   K = 1536; N = 512;  bx = l % 16; by = l / 16; }
  else if (bid < 4224) { int l = bid - 3456; src = Wo;     dst = wqxT + (size_t)1536 * Isz;   K = 1536; N = 512;  bx = l % 16; by = l / 16; }
  else if (bid < 5376) { int l = bid - 4224; src = W_down; dst = wdownT;                      K = 1536; N = 768;  bx = l % 24; by = l / 24; }
  else if (bid < 6144) {
    int base = (bid - 5376) * 1024 + (ty * 32 + tx) * 4;
    #pragma unroll
    for (int e = 0; e < 4; ++e) woutB[base + e] = (bf16_t)W_out[base + e];
    return;
  } else {
    int tid = ty * 32 + tx;
    for (int i = tid; i < 528; i += 256)
      biasA[i] = (i < 512) ? bo[i] : ((i < 520) ? bi[i - 512] : bfv[i - 520]);
    return;
  }
  int n0 = bx * 32, k0 = by * 32;
  #pragma unroll
  for (int j = 0; j < 32; j += 8)
    tile[ty + j][tx] = src[(size_t)(k0 + ty + j) * N + n0 + tx];
  __syncthreads();
  #pragma unroll
  for (int j = 0; j < 32; j += 8)
    dst[(size_t)(n0 + ty + j) * K + k0 + tx] = (bf16_t)(tile[tx][ty + j] * scale);
}

/* ---------------- Wuif composite = W_up @ [Wi|Wf], direct f32 (768 blocks x 1 wave) ---------------- */
__global__ __launch_bounds__(64) void build_wuif(const float* __restrict__ W_up,
                                                 const float* __restrict__ Wi,
                                                 const float* __restrict__ Wf,
                                                 bf16_t* __restrict__ dst /* wupxT + 1536*768 */) {
  int d = blockIdx.x;             /* 0..767 */
  int lane = threadIdx.x;
  float acc[16];
  #pragma unroll
  for (int j = 0; j < 16; ++j) acc[j] = 0.f;
  for (int i = lane; i < Isz; i += 64) {
    float w = W_up[(size_t)d * Isz + i];
    f32x4 wi0 = *(const f32x4*)&Wi[(size_t)i * 8];
    f32x4 wi1 = *(const f32x4*)&Wi[(size_t)i * 8 + 4];
    f32x4 wf0 = *(const f32x4*)&Wf[(size_t)i * 8];
    f32x4 wf1 = *(const f32x4*)&Wf[(size_t)i * 8 + 4];
    #pragma unroll
    for (int j = 0; j < 4; ++j) {
      acc[j]      += w * wi0[j];
      acc[4 + j]  += w * wi1[j];
      acc[8 + j]  += w * wf0[j];
      acc[12 + j] += w * wf1[j];
    }
  }
  #pragma unroll
  for (int j = 0; j < 16; ++j)
    #pragma unroll
    for (int o = 1; o < 64; o <<= 1) acc[j] += __shfl_xor(acc[j], o, 64);
  if (lane == 0) {
    #pragma unroll
    for (int j = 0; j < 16; ++j)
      dst[(size_t)j * Dsz + d] = (bf16_t)acc[j];
  }
}

/* ---------------- LayerNorm ---------------- */
__global__ __launch_bounds__(256) void ln_kernel(const float* __restrict__ x,
                                                 const float* __restrict__ g,
                                                 const float* __restrict__ bta,
                                                 bf16_t* __restrict__ h) {
  size_t tok = blockIdx.x;
  const float* xr = x + tok * Dsz;
  int t = threadIdx.x;
  float v[3]; float s = 0.f;
  #pragma unroll
  for (int i = 0; i < 3; ++i) { v[i] = xr[t + 256 * i]; s += v[i]; }
  s = blockReduceSum256(s);
  float mu = s * (1.f / Dsz);
  float s2 = 0.f;
  #pragma unroll
  for (int i = 0; i < 3; ++i) { float d = v[i] - mu; s2 += d * d; }
  s2 = blockReduceSum256(s2);
  float rs = rsqrtf(s2 * (1.f / Dsz) + 1e-5f);
  #pragma unroll
  for (int i = 0; i < 3; ++i) {
    int col = t + 256 * i;
    h[tok * Dsz + col] = (bf16_t)((v[i] - mu) * rs * g[col] + bta[col]);
  }
}

/* ======================================================================
   256M x 128N m97-style GEMM (proven config: launch_bounds(512,4), VGPR 60).
   EPI: 0 = bf16 out; 3 = f32 out + resid;
        5 = qkvo epilogue (N=2048, grid 512 = exactly 2 blocks/CU);
        6 = up+if epilogue (N=NUX=1664, u stride 1536).
   ====================================================================== */
template<int EPI>
__global__ __launch_bounds__(512, 4) void gemm_mn(const bf16_t* __restrict__ A,
                                                  const bf16_t* __restrict__ Bt,
                                                  void* __restrict__ Cout,
                                                  const void* __restrict__ extra,
                                                  bf16_t* __restrict__ kTg,
                                                  bf16_t* __restrict__ vTg,
                                                  float* __restrict__ ifb,
                                                  int M, int N, int K) {
  __shared__ bf16_t As[256 * 64];
  __shared__ bf16_t Bs[128 * 64];
  const int t = threadIdx.x;
  const int w = t >> 6, l = t & 63;
  const int wm = w >> 1, wn = w & 1;
  const int l15 = l & 15, l4 = l >> 4;

  /* bijective XCD swizzle (nwg % 8 == 0 for all launches) */
  const int gx = gridDim.x;
  const int nwg = gx * gridDim.y;
  const int cpx = nwg >> 3;
  int bid = blockIdx.y * gx + blockIdx.x;
  int wg = (bid & 7) * cpx + (bid >> 3);
  const int tile_m = (wg / gx) * 256;
  const int tile_n = (wg % gx) * 128;

  f32x4 acc[4][4];
  #pragma unroll
  for (int m = 0; m < 4; ++m)
    #pragma unroll
    for (int n = 0; n < 4; ++n) acc[m][n] = (f32x4){0.f, 0.f, 0.f, 0.f};

  for (int k0 = 0; k0 < K; k0 += 64) {
    #pragma unroll
    for (int j = 0; j < 4; ++j) {
      int c = t + j * 512;
      int row = c >> 3;
      int ec = ((c & 7) * 8) ^ ((row & 7) << 3);
      gload16(A + (size_t)(tile_m + row) * K + k0 + ec, (char*)As + (size_t)c * 16);
    }
    #pragma unroll
    for (int j = 0; j < 2; ++j) {
      int c = t + j * 512;
      int row = c >> 3;
      int ec = ((c & 7) * 8) ^ ((row & 7) << 3);
      gload16(Bt + (size_t)(tile_n + row) * K + k0 + ec, (char*)Bs + (size_t)c * 16);
    }
    __syncthreads();
    #pragma unroll
    for (int kk = 0; kk < 2; ++kk) {
      bf16x8 aF[4], bF[4];
      #pragma unroll
      for (int m = 0; m < 4; ++m) {
        int r = wm * 64 + m * 16 + l15;
        aF[m] = *(const bf16x8*)((const char*)As + r * 128 + ((kk * 64 + l4 * 16) ^ ((r & 7) << 4)));
      }
      #pragma unroll
      for (int n = 0; n < 4; ++n) {
        int r = wn * 64 + n * 16 + l15;
        bF[n] = *(const bf16x8*)((const char*)Bs + r * 128 + ((kk * 64 + l4 * 16) ^ ((r & 7) << 4)));
      }
      #pragma unroll
      for (int m = 0; m < 4; ++m)
        #pragma unroll
        for (int n = 0; n < 4; ++n)
          acc[m][n] = __builtin_amdgcn_mfma_f32_16x16x32_bf16(aF[m], bF[n], acc[m][n], 0, 0, 0);
    }
    __syncthreads();
  }

  const int rbase = tile_m + wm * 64 + l4 * 4;
  const int cbase = tile_n + wn * 64 + l15;
  if constexpr (EPI == 5) {
    const float* bias = (const float*)extra;
    #pragma unroll
    for (int m = 0; m < 4; ++m) {
      int row0 = rbase + m * 16;             /* rows row0..row0+3, mult of 4 */
      int bb = row0 >> 11, s0 = row0 & 2047;
      #pragma unroll
      for (int n = 0; n < 4; ++n) {
        int col = cbase + n * 16;
        if (col < 512) {
          #pragma unroll
          for (int j = 0; j < 4; ++j)
            ((bf16_t*)Cout)[(size_t)(row0 + j) * 2048 + col] = (bf16_t)acc[m][n][j];
        } else if (col < 1024) {
          int hd = col - 512;
          bf16x4 pk;
          #pragma unroll
          for (int j = 0; j < 4; ++j) {
            bf16_t bv = (bf16_t)acc[m][n][j];
            ((bf16_t*)Cout)[(size_t)(row0 + j) * 2048 + col] = bv;
            pk[j] = bv;
          }
          *(bf16x4*)(kTg + ((size_t)(bb * 8 + (hd >> 6)) * 64 + (hd & 63)) * Ssz + s0) = pk;
        } else if (col < 1536) {
          int hd = col - 1024;
          bf16x4 pv;
          #pragma unroll
          for (int j = 0; j < 4; ++j) pv[j] = (bf16_t)acc[m][n][j];
          *(bf16x4*)(vTg + ((size_t)(bb * 8 + (hd >> 6)) * 64 + (hd & 63)) * Ssz + s0) = pv;
        } else {
          float b = bias[col - 1536];
          #pragma unroll
          for (int j = 0; j < 4; ++j) {
            float z = acc[m][n][j] + b;
            ((bf16_t*)Cout)[(size_t)(row0 + j) * 2048 + col] = (bf16_t)(1.f / (1.f + __expf(-z)));
          }
        }
      }
    }
  } else if constexpr (EPI == 6) {
    const float* bias = (const float*)extra;   /* biasA+512: [bi(8), bf(8)] */
    #pragma unroll
    for (int m = 0; m < 4; ++m)
      #pragma unroll
      for (int n = 0; n < 4; ++n) {
        int col = cbase + n * 16;
        if (col < 1536) {
          #pragma unroll
          for (int j = 0; j < 4; ++j)
            ((bf16_t*)Cout)[(size_t)(rbase + m * 16 + j) * 1536 + col] = (bf16_t)acc[m][n][j];
        } else if (col < 1552) {
          float b = bias[col - 1536];
          #pragma unroll
          for (int j = 0; j < 4; ++j)
            ifb[(size_t)(rbase + m * 16 + j) * 16 + (col - 1536)] = acc[m][n][j] + b;
        }
      }
  } else {
    #pragma unroll
    for (int m = 0; m < 4; ++m)
      #pragma unroll
      for (int n = 0; n < 4; ++n)
        #pragma unroll
        for (int j = 0; j < 4; ++j) {
          int row = rbase + m * 16 + j;
          int col = cbase + n * 16;
          float v = acc[m][n][j];
          if constexpr (EPI == 0) {
            ((bf16_t*)Cout)[(size_t)row * N + col] = (bf16_t)v;
          } else {  /* EPI == 3 */
            ((float*)Cout)[(size_t)row * N + col] =
                v + ((const float*)extra)[(size_t)row * N + col];
          }
        }
  }
}

/* ---------------- Woc split-K partials: wocT = wdownT @ woutB^T, K sliced x8 ---------------- */
__global__ __launch_bounds__(256) void gemm_woc_part(const bf16_t* __restrict__ A,
                                                     const bf16_t* __restrict__ Bt,
                                                     float* __restrict__ P) {
  __shared__ bf16_t As[128 * 64];
  __shared__ bf16_t Bs[128 * 64];
  const int t = threadIdx.x;
  const int w = t >> 6, l = t & 63;
  const int tile_m = blockIdx.y * 128, tile_n = blockIdx.x * 128;
  const int kz = blockIdx.z;
  const int wr = w >> 1, wc = w & 1;
  const int lrow = l >> 3;
  const int lks = ((l & 7) * 8) ^ (lrow << 3);
  const int l15 = l & 15, l4 = l >> 4;

  f32x4 acc[4][4];
  #pragma unroll
  for (int m = 0; m < 4; ++m)
    #pragma unroll
    for (int n = 0; n < 4; ++n) acc[m][n] = (f32x4){0.f, 0.f, 0.f, 0.f};

  for (int k0 = kz * 192; k0 < kz * 192 + 192; k0 += 64) {
    #pragma unroll
    for (int i = 0; i < 4; ++i) {
      int ch = w * 4 + i;
      int row = ch * 8 + lrow;
      gload16(A  + (size_t)(tile_m + row) * Isz + k0 + lks, &As[ch * 512]);
      gload16(Bt + (size_t)(tile_n + row) * Isz + k0 + lks, &Bs[ch * 512]);
    }
    __syncthreads();
    #pragma unroll
    for (int kk = 0; kk < 2; ++kk) {
      bf16x8 af[4], bfr[4];
      #pragma unroll
      for (int m = 0; m < 4; ++m) {
        int r = wr * 64 + m * 16 + l15;
        af[m] = *(const bf16x8*)&As[r * 64 + ((kk * 32 + l4 * 8) ^ ((r & 7) << 3))];
      }
      #pragma unroll
      for (int n = 0; n < 4; ++n) {
        int r = wc * 64 + n * 16 + l15;
        bfr[n] = *(const bf16x8*)&Bs[r * 64 + ((kk * 32 + l4 * 8) ^ ((r & 7) << 3))];
      }
      #pragma unroll
      for (int m = 0; m < 4; ++m)
        #pragma unroll
        for (int n = 0; n < 4; ++n)
          acc[m][n] = __builtin_amdgcn_mfma_f32_16x16x32_bf16(af[m], bfr[n], acc[m][n], 0, 0, 0);
    }
    __syncthreads();
  }

  const int rbase = tile_m + wr * 64 + l4 * 4;
  const int cbase = tile_n + wc * 64 + l15;
  float* Pz = P + (size_t)kz * 768 * 512;
  #pragma unroll
  for (int m = 0; m < 4; ++m)
    #pragma unroll
    for (int n = 0; n < 4; ++n)
      #pragma unroll
      for (int j = 0; j < 4; ++j)
        Pz[(size_t)(rbase + m * 16 + j) * 512 + cbase + n * 16] = acc[m][n][j];
}

__global__ __launch_bounds__(256) void woc_reduce(const float* __restrict__ P,
                                                  bf16_t* __restrict__ wocT) {
  int i = blockIdx.x * 256 + threadIdx.x;   /* 1536 blocks, 393216 elems */
  float s = 0.f;
  #pragma unroll
  for (int z = 0; z < 8; ++z) s += P[(size_t)z * 393216 + i];
  wocT[i] = (bf16_t)s;
}

/* ---------------- gates pass A ---------------- */
__global__ __launch_bounds__(64) void gates_a(const float* __restrict__ ifb,
                                              float* __restrict__ blocal,
                                              float* __restrict__ Mhat) {
  int bh = blockIdx.x >> 5, c = blockIdx.x & 31;
  int b = bh >> 3, h = bh & 7;
  int lane = threadIdx.x;
  size_t tok = (size_t)b * Ssz + c * Lc + lane;
  float iv = ifb[tok * 16 + h];
  float fv = ifb[tok * 16 + 8 + h];
  float bt = fv;
  #pragma unroll
  for (int d = 1; d < 64; d <<= 1) { float o = __shfl_up(bt, d, 64); if (lane >= d) bt += o; }
  float a = iv - bt;
  float pm = a;
  #pragma unroll
  for (int d = 1; d < 64; d <<= 1) { float o = __shfl_up(pm, d, 64); if (lane >= d) pm = fmaxf(pm, o); }
  blocal[(size_t)bh * Ssz + c * Lc + lane] = bt;
  Mhat[(size_t)bh * Ssz + c * Lc + lane] = bt + pm;
}

/* ---------------- gates pass B ---------------- */
__global__ void gates_b(const float* __restrict__ blocal, const float* __restrict__ Mhat,
                        float* __restrict__ mstart, float* __restrict__ decays,
                        float* __restrict__ mend) {
  int bh = threadIdx.x;
  if (bh < NBH) {
    float M = 0.f;
    for (int c = 0; c < NCH; ++c) {
      mstart[bh * NCH + c] = M;
      float bL = blocal[(size_t)bh * Ssz + c * Lc + 63];
      float Mh = Mhat[(size_t)bh * Ssz + c * Lc + 63];
      float Mn = fmaxf(M + bL, Mh);
      decays[bh * NCH + c] = __expf(M + bL - Mn);
      mend[bh * NCH + c] = Mn;
      M = Mn;
    }
  }
}

/* ---------------- per-chunk state increment, MFMA ---------------- */
__global__ __launch_bounds__(256) void chunk_inc_mfma(const bf16_t* __restrict__ kTg,
                                                      const bf16_t* __restrict__ vTg,
                                                      const float* __restrict__ ifb,
                                                      const float* __restrict__ blocal,
                                                      const float* __restrict__ mend,
                                                      bf16_t* __restrict__ G,
                                                      float* __restrict__ ng) {
  int bh = blockIdx.x >> 5, c = blockIdx.x & 31;
  int b = bh >> 3, h = bh & 7;
  __shared__ bf16_t Vt[64 * 64];
  __shared__ bf16_t Kw[64 * 64];
  __shared__ float wsh[64];
  const int t = threadIdx.x, w = t >> 6, l = t & 63;
  const int l15 = l & 15, l4 = l >> 4;
  if (t < 64) {
    float mL = mend[bh * NCH + c];
    float bL = blocal[(size_t)bh * Ssz + c * Lc + 63];
    float bt = blocal[(size_t)bh * Ssz + c * Lc + t];
    float iv = ifb[((size_t)b * Ssz + c * Lc + t) * 16 + h];
    wsh[t] = __expf(iv + bL - bt - mL);
  }
  __syncthreads();
  {
    const int r = l >> 3, c8 = (l & 7) * 8;
    #pragma unroll
    for (int i = 0; i < 2; ++i) {
      int seg = w * 2 + i, row = seg * 8 + r;
      gload16(vTg + ((size_t)bh * 64 + row) * Ssz + c * 64 + c8, &Vt[seg * 512]);
    }
    #pragma unroll
    for (int i = 0; i < 2; ++i) {
      int e = t + i * 256; int row = e >> 3, c0 = (e & 7) * 8;
      bf16x8 kv = *(const bf16x8*)(kTg + ((size_t)bh * 64 + row) * Ssz + c * 64 + c0);
      #pragma unroll
      for (int j = 0; j < 8; ++j) kv[j] = (bf16_t)((float)kv[j] * wsh[c0 + j]);
      *(bf16x8*)&Kw[row * 64 + c0] = kv;
    }
  }
  __syncthreads();
  f32x4 acc[4];
  #pragma unroll
  for (int n = 0; n < 4; ++n) acc[n] = (f32x4){0.f, 0.f, 0.f, 0.f};
  #pragma unroll
  for (int kk = 0; kk < 2; ++kk) {
    bf16x8 af = *(const bf16x8*)&Vt[(w * 16 + l15) * 64 + kk * 32 + l4 * 8];
    #pragma unroll
    for (int n = 0; n < 4; ++n) {
      bf16x8 bfr = *(const bf16x8*)&Kw[(n * 16 + l15) * 64 + kk * 32 + l4 * 8];
      acc[n] = __builtin_amdgcn_mfma_f32_16x16x32_bf16(af, bfr, acc[n], 0, 0, 0);
    }
  }
  size_t gb = ((size_t)bh * NCH + c) * 4096;
  #pragma unroll
  for (int n = 0; n < 4; ++n)
    #pragma unroll
    for (int j = 0; j < 4; ++j) {
      int row = w * 16 + l4 * 4 + j;
      int col = n * 16 + l15;
      G[gb + (size_t)row * 64 + col] = (bf16_t)acc[n][j];
    }
  if (t < 64) {
    float s = 0.f;
    for (int s2 = 0; s2 < 64; ++s2) s += (float)Kw[t * 64 + s2];
    ng[((size_t)bh * NCH + c) * 64 + t] = s;
  }
}

/* ---------------- state scan ---------------- */
__global__ __launch_bounds__(256) void state_scan(const bf16_t* __restrict__ G,
                                                  const float* __restrict__ ng,
                                                  const float* __restrict__ decays,
                                                  bf16_t* __restrict__ CstB,
                                                  float* __restrict__ nst) {
  int gid = blockIdx.x;
  if (gid < 512) {
    int idx = gid * 256 + threadIdx.x;
    int bh = idx >> 12, e = idx & 4095;
    const float* d = decays + bh * NCH;
    float C = 0.f;
    #pragma unroll
    for (int c = 0; c < NCH; ++c) {
      size_t o = ((size_t)bh * NCH + c) * 4096 + e;
      CstB[o] = (bf16_t)C;
      C = d[c] * C + (float)G[o];
    }
  } else {
    int idx = (gid - 512) * 256 + threadIdx.x;
    int bh = idx >> 6, e = idx & 63;
    const float* d = decays + bh * NCH;
    float n = 0.f;
    #pragma unroll
    for (int c = 0; c < NCH; ++c) {
      size_t o = ((size_t)bh * NCH + c) * 64 + e;
      nst[o] = n;
      n = d[c] * n + ng[o];
    }
  }
}

/* ---------------- intra-chunk outputs + fused group-norm/out-gate ---------------- */
__global__ __launch_bounds__(256) void intra_mfma(const bf16_t* __restrict__ qkvo,
                                                  const bf16_t* __restrict__ vTg,
                                                  const bf16_t* __restrict__ CstB,
                                                  const float* __restrict__ nst,
                                                  const float* __restrict__ ifb,
                                                  const float* __restrict__ blocal,
                                                  const float* __restrict__ Mhat,
                                                  const float* __restrict__ mstart,
                                                  const float* __restrict__ mhg,
                                                  bf16_t* __restrict__ gated) {
  int bh = blockIdx.x >> 5, c = blockIdx.x & 31;
  int b = bh >> 3, h = bh & 7;
  __shared__ bf16_t qs[64 * 64];
  __shared__ bf16_t ks[64 * 64];
  __shared__ bf16_t vTs[64 * 64];
  __shared__ bf16_t Cs[64 * 64];
  __shared__ float nin[64], den_s[64], ssrc[64], sdst[64], esc[64];
  const int t = threadIdx.x, w = t >> 6, l = t & 63;
  const int l15 = l & 15, l4 = l >> 4;
  const size_t tok0 = (size_t)b * Ssz + c * Lc;
  const size_t cbase = ((size_t)bh * NCH + c) * 4096;

  if (t < 64) {
    nin[t] = nst[((size_t)bh * NCH + c) * 64 + t];
    float bt = blocal[(size_t)bh * Ssz + c * Lc + t];
    float Mh2 = Mhat[(size_t)bh * Ssz + c * Lc + t];
    float Mc = mstart[bh * NCH + c];
    float iv = ifb[(tok0 + t) * 16 + h];
    float mt = fmaxf(Mc + bt, Mh2);
    ssrc[t] = iv - bt;
    sdst[t] = bt - mt;
    esc[t]  = __expf(Mc + bt - mt);
  }
  {
    const int r = l >> 3, c8 = (l & 7) * 8;
    #pragma unroll
    for (int i = 0; i < 2; ++i) {
      int seg = w * 2 + i, row = seg * 8 + r;
      gload16(qkvo + (tok0 + row) * 2048 + h * 64 + c8,          &qs[seg * 512]);
      gload16(qkvo + (tok0 + row) * 2048 + 512 + h * 64 + c8,    &ks[seg * 512]);
      gload16(vTg + ((size_t)bh * 64 + row) * Ssz + c * 64 + c8, &vTs[seg * 512]);
      gload16(CstB + cbase + seg * 512 + l * 8,                  &Cs[seg * 512]);
    }
  }
  __syncthreads();

  f32x4 aS[4];
  #pragma unroll
  for (int n = 0; n < 4; ++n) aS[n] = (f32x4){0.f, 0.f, 0.f, 0.f};
  #pragma unroll
  for (int kk = 0; kk < 2; ++kk) {
    bf16x8 af = *(const bf16x8*)&qs[(w * 16 + l15) * 64 + kk * 32 + l4 * 8];
    #pragma unroll
    for (int n = 0; n < 4; ++n) {
      bf16x8 bfr = *(const bf16x8*)&ks[(n * 16 + l15) * 64 + kk * 32 + l4 * 8];
      aS[n] = __builtin_amdgcn_mfma_f32_16x16x32_bf16(af, bfr, aS[n], 0, 0, 0);
    }
  }
  {
    int row = w * 16 + (l >> 2);
    int c0 = (l & 3) * 16;
    float e = esc[row];
    #pragma unroll
    for (int i2 = 0; i2 < 2; ++i2) {
      bf16x8 v8 = *(const bf16x8*)&qs[row * 64 + c0 + i2 * 8];
      #pragma unroll
      for (int j = 0; j < 8; ++j) v8[j] = (bf16_t)((float)v8[j] * e);
      *(bf16x8*)&qs[row * 64 + c0 + i2 * 8] = v8;
    }
  }
  float rs[4] = {0.f, 0.f, 0.f, 0.f};
  #pragma unroll
  for (int n = 0; n < 4; ++n) {
    int col = n * 16 + l15;
    float es = ssrc[col];
    #pragma unroll
    for (int j = 0; j < 4; ++j) {
      int row = w * 16 + l4 * 4 + j;
      float p = (col <= row) ? aS[n][j] * __expf(es + sdst[row]) : 0.f;
      aS[n][j] = p;
      rs[j] += p;
    }
  }
  #pragma unroll
  for (int j = 0; j < 4; ++j) {
    rs[j] += __shfl_xor(rs[j], 1, 64);
    rs[j] += __shfl_xor(rs[j], 2, 64);
    rs[j] += __shfl_xor(rs[j], 4, 64);
    rs[j] += __shfl_xor(rs[j], 8, 64);
  }
  if (l15 == 0) {
    #pragma unroll
    for (int j = 0; j < 4; ++j) den_s[w * 16 + l4 * 4 + j] = rs[j];
  }
  __syncthreads();

  #pragma unroll
  for (int n = 0; n < 4; ++n)
    #pragma unroll
    for (int j = 0; j < 4; ++j)
      ks[(w * 16 + l4 * 4 + j) * 64 + n * 16 + l15] = (bf16_t)aS[n][j];

  {
    int row = w * 16 + (l >> 2);
    int c0 = (l & 3) * 16;
    float part = 0.f;
    #pragma unroll
    for (int i2 = 0; i2 < 16; ++i2)
      part += (float)qs[row * 64 + c0 + i2] * nin[c0 + i2];
    part += __shfl_xor(part, 1, 64);
    part += __shfl_xor(part, 2, 64);
    if ((l & 3) == 0)
      den_s[row] = fmaxf(fabsf(den_s[row] + part), 1.0f);
  }
  __syncthreads();

  f32x4 aO[4];
  #pragma unroll
  for (int n = 0; n < 4; ++n) aO[n] = (f32x4){0.f, 0.f, 0.f, 0.f};
  #pragma unroll
  for (int kk = 0; kk < 2; ++kk) {
    bf16x8 afP = *(const bf16x8*)&ks[(w * 16 + l15) * 64 + kk * 32 + l4 * 8];
    bf16x8 afQ = *(const bf16x8*)&qs[(w * 16 + l15) * 64 + kk * 32 + l4 * 8];
    #pragma unroll
    for (int n = 0; n < 4; ++n) {
      bf16x8 bV = *(const bf16x8*)&vTs[(n * 16 + l15) * 64 + kk * 32 + l4 * 8];
      bf16x8 bC = *(const bf16x8*)&Cs[(n * 16 + l15) * 64 + kk * 32 + l4 * 8];
      aO[n] = __builtin_amdgcn_mfma_f32_16x16x32_bf16(afP, bV, aO[n], 0, 0, 0);
      aO[n] = __builtin_amdgcn_mfma_f32_16x16x32_bf16(afQ, bC, aO[n], 0, 0, 0);
    }
  }

  /* fused per-row group-norm (64 cols in 16 lanes x 4 regs) + sigmoid(og)*mh_g */
  #pragma unroll
  for (int j = 0; j < 4; ++j) {
    int row = w * 16 + l4 * 4 + j;
    float rinv = 1.f / den_s[row];
    float ov[4];
    #pragma unroll
    for (int n = 0; n < 4; ++n) ov[n] = aO[n][j] * rinv;
    float s = ov[0] + ov[1] + ov[2] + ov[3];
    s += __shfl_xor(s, 1, 64); s += __shfl_xor(s, 2, 64);
    s += __shfl_xor(s, 4, 64); s += __shfl_xor(s, 8, 64);
    float mu = s * (1.f / 64.f);
    float s2 = 0.f;
    #pragma unroll
    for (int n = 0; n < 4; ++n) { float d = ov[n] - mu; s2 += d * d; }
    s2 += __shfl_xor(s2, 1, 64); s2 += __shfl_xor(s2, 2, 64);
    s2 += __shfl_xor(s2, 4, 64); s2 += __shfl_xor(s2, 8, 64);
    float rstd = rsqrtf(s2 * (1.f / 64.f) + 1e-5f);
    size_t tok = tok0 + row;
    #pragma unroll
    for (int n = 0; n < 4; ++n) {
      int colh = n * 16 + l15;
      float og = (float)qkvo[tok * 2048 + 1536 + h * 64 + colh];
      float hn = (ov[n] - mu) * rstd * mhg[h * 64 + colh];
      gated[tok * 512 + h * 64 + colh] = (bf16_t)(og * hn);
    }
  }
}

/* ---------------- launcher ---------------- */
extern "C" void kernel_launch(void* const* d_in, const int* in_sizes, int n_in,
                              void* d_out, int out_size, void* d_ws, size_t ws_size,
                              hipStream_t stream) {
  const float* x     = (const float*)d_in[0];
  const float* ln_g  = (const float*)d_in[1];
  const float* ln_b  = (const float*)d_in[2];
  const float* W_up  = (const float*)d_in[3];
  const float* W_down= (const float*)d_in[4];
  const float* Wq    = (const float*)d_in[5];
  const float* Wk    = (const float*)d_in[6];
  const float* Wv    = (const float*)d_in[7];
  const float* Wi    = (const float*)d_in[8];
  const float* bi    = (const float*)d_in[9];
  const float* Wf    = (const float*)d_in[10];
  const float* bfv   = (const float*)d_in[11];
  const float* Wo    = (const float*)d_in[12];
  const float* bo    = (const float*)d_in[13];
  const float* mh_g  = (const float*)d_in[14];
  const float* W_out = (const float*)d_in[15];

  char* ws = (char*)d_ws;
  bf16_t* hbuf   = (bf16_t*)(ws + OFF_H);
  bf16_t* wupxT  = (bf16_t*)(ws + OFF_WUPX);
  bf16_t* wqxT   = (bf16_t*)(ws + OFF_WQX);
  bf16_t* wdownT = (bf16_t*)(ws + OFF_WDOWNT);
  bf16_t* wocT   = (bf16_t*)(ws + OFF_WOC);
  float*  biasA  = (float*)(ws + OFF_BIAS);
  bf16_t* ubuf   = (bf16_t*)(ws + OFF_U);
  bf16_t* qkvob  = (bf16_t*)(ws + OFF_QKVO);
  bf16_t* woutB  = (bf16_t*)(ws + OFF_WOUTB);
  float*  wocP   = (float*)(ws + OFF_WOCP);
  bf16_t* kTg    = (bf16_t*)(ws + OFF_KT);
  bf16_t* vTg    = (bf16_t*)(ws + OFF_VT);
  float*  ifb    = (float*)(ws + OFF_IFB);
  float*  bloc   = (float*)(ws + OFF_BLOC);
  float*  Mh     = (float*)(ws + OFF_MHAT);
  float*  mst    = (float*)(ws + OFF_MST);
  float*  decays = (float*)(ws + OFF_DEC);
  float*  mendb  = (float*)(ws + OFF_MEND);
  float*  ngbuf  = (float*)(ws + OFF_NG);
  float*  nst    = (float*)(ws + OFF_NST);
  bf16_t* CstB   = (bf16_t*)(ws + OFF_CSTB);
  bf16_t* Gbuf   = (bf16_t*)(ws + OFF_G);
  bf16_t* gbuf   = (bf16_t*)(ws + OFF_GATED);

  /* one merged weight-prep kernel + parallel Wuif + split-K Woc */
  prep_weights<<<6145, dim3(32, 8), 0, stream>>>(W_up, Wq, Wk, Wv, Wo, W_down, W_out,
                                                 bo, bi, bfv, wupxT, wqxT, wdownT, woutB, biasA);
  build_wuif<<<Dsz, 64, 0, stream>>>(W_up, Wi, Wf, wupxT + (size_t)1536 * Dsz);
  gemm_woc_part<<<dim3(4, 6, 8), 256, 0, stream>>>(wdownT, woutB, wocP);
  woc_reduce<<<1536, 256, 0, stream>>>(wocP, wocT);

  ln_kernel<<<NTOK, 256, 0, stream>>>(x, ln_g, ln_b, hbuf);

  /* fused up-proj + i/f-gate projection (composite weight), grid 416 */
  gemm_mn<6><<<dim3(NUX / 128, NTOK / 256), 512, 0, stream>>>(hbuf, wupxT, ubuf, biasA + 512, nullptr, nullptr, ifb, NTOK, NUX, Dsz);
  /* fused qkvo + kv-transpose + sigmoid(o), grid 512 = exactly 2 blocks/CU */
  gemm_mn<5><<<dim3(2048 / 128, NTOK / 256), 512, 0, stream>>>(ubuf, wqxT, qkvob, biasA, kTg, vTg, nullptr, NTOK, 2048, Isz);

  gates_a<<<NBH * NCH, 64, 0, stream>>>(ifb, bloc, Mh);
  gates_b<<<1, 32, 0, stream>>>(bloc, Mh, mst, decays, mendb);
  chunk_inc_mfma<<<NBH * NCH, 256, 0, stream>>>(kTg, vTg, ifb, bloc, mendb, Gbuf, ngbuf);
  state_scan<<<520, 256, 0, stream>>>(Gbuf, ngbuf, decays, CstB, nst);
  intra_mfma<<<NBH * NCH, 256, 0, stream>>>(qkvob, vTg, CstB, nst, ifb, bloc, Mh, mst, mh_g, gbuf);

  /* fused: out = x + gated @ (W_out @ W_down), K=512 */
  gemm_mn<3><<<dim3(Dsz / 128, NTOK / 256), 512, 0, stream>>>(gbuf, wocT, (float*)d_out, x, nullptr, nullptr, nullptr, NTOK, Dsz, 512);
}

// Round 13
// 163.203 us; speedup vs baseline: 1.4289x; 1.0729x over previous
//
#include <hip/hip_runtime.h>
#include <hip/hip_bf16.h>
#include <stdint.h>
#include <stddef.h>

typedef __bf16 bf16_t;
typedef __bf16 bf16x4 __attribute__((ext_vector_type(4)));
typedef __bf16 bf16x8 __attribute__((ext_vector_type(8)));
typedef float  f32x4  __attribute__((ext_vector_type(4)));

#define Bsz  4
#define Ssz  2048
#define Dsz  768
#define Isz  1536
#define Hn   8
#define HDsz 64
#define NTOK (Bsz*Ssz)      /* 8192 */
#define Lc   64
#define NCH  (Ssz/Lc)       /* 32 */
#define NBH  (Bsz*Hn)       /* 32 */

/* ---------------- workspace layout (bytes) ---------------- */
#define OFF_H      ((size_t)0)                    /* 12.58M; wocP & CstB alias */
#define OFF_WQX    ((size_t)12582912)             /* 2048x1536 bf16 = 6.29M (comp input) */
#define OFF_WQC    ((size_t)18874368)             /* 2048x768 bf16 = 3.15M (composite) */
#define OFF_WDOWNT ((size_t)22020096)             /* 2.36M */
#define OFF_WOC    ((size_t)24379392)             /* 768x512 bf16 = 0.79M */
#define OFF_WUPB   ((size_t)25165824)             /* 768x1536 bf16 = 2.36M */
#define OFF_WUIF   ((size_t)27525120)             /* 16x768 bf16 = 24.6K */
#define OFF_BIAS   ((size_t)27549696)             /* 528 f32, pad 4K */
#define OFF_WOUTB  ((size_t)27553792)             /* 512x1536 bf16 = 1.57M */
#define OFF_QKVO   ((size_t)29126656)             /* 8192x2048 bf16 = 33.55M; compP aliases */
#define OFF_KT     ((size_t)62681088)             /* 8.39M */
#define OFF_VT     ((size_t)71069696)             /* 8.39M */
#define OFF_GATED  ((size_t)79458304)             /* 8.39M */
#define OFF_G      ((size_t)87846912)             /* 8.39M */
#define OFF_IFB    ((size_t)96235520)             /* 0.52M */
#define OFF_BLOC   ((size_t)96759808)
#define OFF_MHAT   ((size_t)97021952)
#define OFF_MST    ((size_t)97284096)
#define OFF_DEC    ((size_t)97288192)
#define OFF_MEND   ((size_t)97292288)
#define OFF_NG     ((size_t)97296384)
#define OFF_NST    ((size_t)97558528)             /* end 97820672 */
/* aliases (dead before region overwritten) */
#define OFF_WOCP   OFF_H                          /* 8x768x512 f32 = 12.58M, dead before ln */
#define OFF_CSTB   OFF_H                          /* 8.39M, after qkvo-gemm (h dead) */
#define OFF_COMPP  OFF_QKVO                       /* 4x2048x768 f32 = 25.2M, dead before qkvo write */

/* ---------------- helpers ---------------- */
__device__ __forceinline__ void gload16(const void* gsrc, void* ldst) {
  __builtin_amdgcn_global_load_lds(
      (const __attribute__((address_space(1))) void*)gsrc,
      (__attribute__((address_space(3))) void*)ldst, 16, 0, 0);
}

__device__ __forceinline__ float blockReduceSum256(float v) {
  #pragma unroll
  for (int o = 1; o < 64; o <<= 1) v += __shfl_xor(v, o, 64);
  __shared__ float sh[4];
  int wid = threadIdx.x >> 6;
  __syncthreads();
  if ((threadIdx.x & 63) == 0) sh[wid] = v;
  __syncthreads();
  return sh[0] + sh[1] + sh[2] + sh[3];
}

/* ======================================================================
   prep_weights — all weight transposes/casts/bias in ONE kernel. grid 6145:
     [0,768)      Wq  -> wqxT
     [768,1536)   Wk*0.125 -> wqxT+512*Isz
     [1536,2304)  Wv  -> wqxT+1024*Isz
     [2304,3072)  Wo  -> wqxT+1536*Isz
     [3072,4224)  W_down transpose -> wdownT
     [4224,4992)  W_out cast -> woutB
     [4992,6144)  W_up cast -> wupB (row-major)
     [6144]       bias pack [bo, bi, bf]
   ====================================================================== */
__global__ __launch_bounds__(256) void prep_weights(
    const float* __restrict__ W_up, const float* __restrict__ Wq,
    const float* __restrict__ Wk, const float* __restrict__ Wv,
    const float* __restrict__ Wo, const float* __restrict__ W_down,
    const float* __restrict__ W_out, const float* __restrict__ bo,
    const float* __restrict__ bi, const float* __restrict__ bfv,
    bf16_t* __restrict__ wqxT, bf16_t* __restrict__ wdownT,
    bf16_t* __restrict__ woutB, bf16_t* __restrict__ wupB,
    float* __restrict__ biasA) {
  __shared__ float tile[32][33];
  const int bid = blockIdx.x;
  const int tx = threadIdx.x, ty = threadIdx.y;
  const float* src; bf16_t* dst; int K, N, bx, by; float scale = 1.f;
  if (bid < 768)       { int l = bid;        src = Wq;     dst = wqxT;                      K = 1536; N = 512; bx = l % 16; by = l / 16; }
  else if (bid < 1536) { int l = bid - 768;  src = Wk;     dst = wqxT + (size_t)512 * Isz;  K = 1536; N = 512; bx = l % 16; by = l / 16; scale = 0.125f; }
  else if (bid < 2304) { int l = bid - 1536; src = Wv;     dst = wqxT + (size_t)1024 * Isz; K = 1536; N = 512; bx = l % 16; by = l / 16; }
  else if (bid < 3072) { int l = bid - 2304; src = Wo;     dst = wqxT + (size_t)1536 * Isz; K = 1536; N = 512; bx = l % 16; by = l / 16; }
  else if (bid < 4224) { int l = bid - 3072; src = W_down; dst = wdownT;                    K = 1536; N = 768; bx = l % 24; by = l / 24; }
  else if (bid < 4992) {
    int base = (bid - 4224) * 1024 + (ty * 32 + tx) * 4;
    #pragma unroll
    for (int e = 0; e < 4; ++e) woutB[base + e] = (bf16_t)W_out[base + e];
    return;
  } else if (bid < 6144) {
    int base = (bid - 4992) * 1024 + (ty * 32 + tx) * 4;
    #pragma unroll
    for (int e = 0; e < 4; ++e) wupB[base + e] = (bf16_t)W_up[base + e];
    return;
  } else {
    int tid = ty * 32 + tx;
    for (int i = tid; i < 528; i += 256)
      biasA[i] = (i < 512) ? bo[i] : ((i < 520) ? bi[i - 512] : bfv[i - 520]);
    return;
  }
  int n0 = bx * 32, k0 = by * 32;
  #pragma unroll
  for (int j = 0; j < 32; j += 8)
    tile[ty + j][tx] = src[(size_t)(k0 + ty + j) * N + n0 + tx];
  __syncthreads();
  #pragma unroll
  for (int j = 0; j < 32; j += 8)
    dst[(size_t)(n0 + ty + j) * K + k0 + tx] = (bf16_t)(tile[tx][ty + j] * scale);
}

/* ---------------- Wuif composite = W_up @ [Wi|Wf], direct f32 ---------------- */
__global__ __launch_bounds__(64) void build_wuif(const float* __restrict__ W_up,
                                                 const float* __restrict__ Wi,
                                                 const float* __restrict__ Wf,
                                                 bf16_t* __restrict__ dst /* (16,768) */) {
  int d = blockIdx.x;
  int lane = threadIdx.x;
  float acc[16];
  #pragma unroll
  for (int j = 0; j < 16; ++j) acc[j] = 0.f;
  for (int i = lane; i < Isz; i += 64) {
    float w = W_up[(size_t)d * Isz + i];
    f32x4 wi0 = *(const f32x4*)&Wi[(size_t)i * 8];
    f32x4 wi1 = *(const f32x4*)&Wi[(size_t)i * 8 + 4];
    f32x4 wf0 = *(const f32x4*)&Wf[(size_t)i * 8];
    f32x4 wf1 = *(const f32x4*)&Wf[(size_t)i * 8 + 4];
    #pragma unroll
    for (int j = 0; j < 4; ++j) {
      acc[j]      += w * wi0[j];
      acc[4 + j]  += w * wi1[j];
      acc[8 + j]  += w * wf0[j];
      acc[12 + j] += w * wf1[j];
    }
  }
  #pragma unroll
  for (int j = 0; j < 16; ++j)
    #pragma unroll
    for (int o = 1; o < 64; o <<= 1) acc[j] += __shfl_xor(acc[j], o, 64);
  if (lane == 0) {
    #pragma unroll
    for (int j = 0; j < 16; ++j)
      dst[(size_t)j * Dsz + d] = (bf16_t)acc[j];
  }
}

/* ---------------- split-K 128^2 GEMM partials: P[z] = A@Bt^T over K-slice ---------------- */
__global__ __launch_bounds__(256) void gemm_partk(const bf16_t* __restrict__ A,
                                                  const bf16_t* __restrict__ Bt,
                                                  float* __restrict__ P,
                                                  int M, int N, int Ktot, int kslice) {
  __shared__ bf16_t As[128 * 64];
  __shared__ bf16_t Bs[128 * 64];
  const int t = threadIdx.x;
  const int w = t >> 6, l = t & 63;
  const int tile_m = blockIdx.y * 128, tile_n = blockIdx.x * 128;
  const int kz = blockIdx.z;
  const int wr = w >> 1, wc = w & 1;
  const int lrow = l >> 3;
  const int lks = ((l & 7) * 8) ^ (lrow << 3);
  const int l15 = l & 15, l4 = l >> 4;

  f32x4 acc[4][4];
  #pragma unroll
  for (int m = 0; m < 4; ++m)
    #pragma unroll
    for (int n = 0; n < 4; ++n) acc[m][n] = (f32x4){0.f, 0.f, 0.f, 0.f};

  for (int k0 = kz * kslice; k0 < kz * kslice + kslice; k0 += 64) {
    #pragma unroll
    for (int i = 0; i < 4; ++i) {
      int ch = w * 4 + i;
      int row = ch * 8 + lrow;
      gload16(A  + (size_t)(tile_m + row) * Ktot + k0 + lks, &As[ch * 512]);
      gload16(Bt + (size_t)(tile_n + row) * Ktot + k0 + lks, &Bs[ch * 512]);
    }
    __syncthreads();
    #pragma unroll
    for (int kk = 0; kk < 2; ++kk) {
      bf16x8 af[4], bfr[4];
      #pragma unroll
      for (int m = 0; m < 4; ++m) {
        int r = wr * 64 + m * 16 + l15;
        af[m] = *(const bf16x8*)&As[r * 64 + ((kk * 32 + l4 * 8) ^ ((r & 7) << 3))];
      }
      #pragma unroll
      for (int n = 0; n < 4; ++n) {
        int r = wc * 64 + n * 16 + l15;
        bfr[n] = *(const bf16x8*)&Bs[r * 64 + ((kk * 32 + l4 * 8) ^ ((r & 7) << 3))];
      }
      #pragma unroll
      for (int m = 0; m < 4; ++m)
        #pragma unroll
        for (int n = 0; n < 4; ++n)
          acc[m][n] = __builtin_amdgcn_mfma_f32_16x16x32_bf16(af[m], bfr[n], acc[m][n], 0, 0, 0);
    }
    __syncthreads();
  }

  const int rbase = tile_m + wr * 64 + l4 * 4;
  const int cbase = tile_n + wc * 64 + l15;
  float* Pz = P + (size_t)kz * M * N;
  #pragma unroll
  for (int m = 0; m < 4; ++m)
    #pragma unroll
    for (int n = 0; n < 4; ++n)
      #pragma unroll
      for (int j = 0; j < 4; ++j)
        Pz[(size_t)(rbase + m * 16 + j) * N + cbase + n * 16] = acc[m][n][j];
}

__global__ __launch_bounds__(256) void partk_reduce(const float* __restrict__ P,
                                                    bf16_t* __restrict__ out,
                                                    int nelem, int nz) {
  int i = blockIdx.x * 256 + threadIdx.x;
  if (i < nelem) {
    float s = 0.f;
    for (int z = 0; z < nz; ++z) s += P[(size_t)z * nelem + i];
    out[i] = (bf16_t)s;
  }
}

/* ---------------- LayerNorm ---------------- */
__global__ __launch_bounds__(256) void ln_kernel(const float* __restrict__ x,
                                                 const float* __restrict__ g,
                                                 const float* __restrict__ bta,
                                                 bf16_t* __restrict__ h) {
  size_t tok = blockIdx.x;
  const float* xr = x + tok * Dsz;
  int t = threadIdx.x;
  float v[3]; float s = 0.f;
  #pragma unroll
  for (int i = 0; i < 3; ++i) { v[i] = xr[t + 256 * i]; s += v[i]; }
  s = blockReduceSum256(s);
  float mu = s * (1.f / Dsz);
  float s2 = 0.f;
  #pragma unroll
  for (int i = 0; i < 3; ++i) { float d = v[i] - mu; s2 += d * d; }
  s2 = blockReduceSum256(s2);
  float rs = rsqrtf(s2 * (1.f / Dsz) + 1e-5f);
  #pragma unroll
  for (int i = 0; i < 3; ++i) {
    int col = t + 256 * i;
    h[tok * Dsz + col] = (bf16_t)((v[i] - mu) * rs * g[col] + bta[col]);
  }
}

/* ---------------- i/f gate projection: ifb = h @ Wuif + bias (M=8192,N=16,K=768) ---------------- */
__global__ __launch_bounds__(256) void ifproj_mfma(const bf16_t* __restrict__ h,
                                                   const bf16_t* __restrict__ wuifT,
                                                   const float* __restrict__ bi,
                                                   const float* __restrict__ bfv,
                                                   float* __restrict__ ifb) {
  __shared__ bf16_t As[128 * 64];
  __shared__ bf16_t Bs[16 * 64];
  const int t = threadIdx.x, w = t >> 6, l = t & 63;
  const int l15 = l & 15, l4 = l >> 4;
  const int lrow = l >> 3, lk = (l & 7) * 8;
  const int tile_m = blockIdx.x * 128;
  f32x4 acc[2];
  acc[0] = (f32x4){0.f, 0.f, 0.f, 0.f};
  acc[1] = (f32x4){0.f, 0.f, 0.f, 0.f};

  for (int k0 = 0; k0 < Dsz; k0 += 64) {
    #pragma unroll
    for (int i = 0; i < 4; ++i) {
      int ch = w * 4 + i;
      int row = ch * 8 + lrow;
      gload16(h + (size_t)(tile_m + row) * Dsz + k0 + lk, &As[ch * 512]);
    }
    if (t < 128) {
      int rr = t >> 3, c0 = (t & 7) * 8;
      *(bf16x8*)&Bs[rr * 64 + c0] = *(const bf16x8*)(wuifT + (size_t)rr * Dsz + k0 + c0);
    }
    __syncthreads();
    #pragma unroll
    for (int kk = 0; kk < 2; ++kk) {
      bf16x8 bfr = *(const bf16x8*)&Bs[l15 * 64 + kk * 32 + l4 * 8];
      #pragma unroll
      for (int m = 0; m < 2; ++m) {
        bf16x8 af = *(const bf16x8*)&As[(w * 32 + m * 16 + l15) * 64 + kk * 32 + l4 * 8];
        acc[m] = __builtin_amdgcn_mfma_f32_16x16x32_bf16(af, bfr, acc[m], 0, 0, 0);
      }
    }
    __syncthreads();
  }
  float bias = (l15 < 8) ? bi[l15] : bfv[l15 - 8];
  #pragma unroll
  for (int m = 0; m < 2; ++m)
    #pragma unroll
    for (int j = 0; j < 4; ++j) {
      int row = tile_m + w * 32 + m * 16 + l4 * 4 + j;
      ifb[(size_t)row * 16 + l15] = acc[m][j] + bias;
    }
}

/* ======================================================================
   256M x 128N m97-style GEMM (proven: launch_bounds(512,4), VGPR 60).
   EPI: 3 = f32 out + resid; 5 = qkvo epilogue (N=2048, K=768 composite).
   ====================================================================== */
template<int EPI>
__global__ __launch_bounds__(512, 4) void gemm_mn(const bf16_t* __restrict__ A,
                                                  const bf16_t* __restrict__ Bt,
                                                  void* __restrict__ Cout,
                                                  const void* __restrict__ extra,
                                                  bf16_t* __restrict__ kTg,
                                                  bf16_t* __restrict__ vTg,
                                                  int M, int N, int K) {
  __shared__ bf16_t As[256 * 64];
  __shared__ bf16_t Bs[128 * 64];
  const int t = threadIdx.x;
  const int w = t >> 6, l = t & 63;
  const int wm = w >> 1, wn = w & 1;
  const int l15 = l & 15, l4 = l >> 4;

  /* bijective XCD swizzle (nwg % 8 == 0 for all launches) */
  const int gx = gridDim.x;
  const int nwg = gx * gridDim.y;
  const int cpx = nwg >> 3;
  int bid = blockIdx.y * gx + blockIdx.x;
  int wg = (bid & 7) * cpx + (bid >> 3);
  const int tile_m = (wg / gx) * 256;
  const int tile_n = (wg % gx) * 128;

  f32x4 acc[4][4];
  #pragma unroll
  for (int m = 0; m < 4; ++m)
    #pragma unroll
    for (int n = 0; n < 4; ++n) acc[m][n] = (f32x4){0.f, 0.f, 0.f, 0.f};

  for (int k0 = 0; k0 < K; k0 += 64) {
    #pragma unroll
    for (int j = 0; j < 4; ++j) {
      int c = t + j * 512;
      int row = c >> 3;
      int ec = ((c & 7) * 8) ^ ((row & 7) << 3);
      gload16(A + (size_t)(tile_m + row) * K + k0 + ec, (char*)As + (size_t)c * 16);
    }
    #pragma unroll
    for (int j = 0; j < 2; ++j) {
      int c = t + j * 512;
      int row = c >> 3;
      int ec = ((c & 7) * 8) ^ ((row & 7) << 3);
      gload16(Bt + (size_t)(tile_n + row) * K + k0 + ec, (char*)Bs + (size_t)c * 16);
    }
    __syncthreads();
    #pragma unroll
    for (int kk = 0; kk < 2; ++kk) {
      bf16x8 aF[4], bF[4];
      #pragma unroll
      for (int m = 0; m < 4; ++m) {
        int r = wm * 64 + m * 16 + l15;
        aF[m] = *(const bf16x8*)((const char*)As + r * 128 + ((kk * 64 + l4 * 16) ^ ((r & 7) << 4)));
      }
      #pragma unroll
      for (int n = 0; n < 4; ++n) {
        int r = wn * 64 + n * 16 + l15;
        bF[n] = *(const bf16x8*)((const char*)Bs + r * 128 + ((kk * 64 + l4 * 16) ^ ((r & 7) << 4)));
      }
      #pragma unroll
      for (int m = 0; m < 4; ++m)
        #pragma unroll
        for (int n = 0; n < 4; ++n)
          acc[m][n] = __builtin_amdgcn_mfma_f32_16x16x32_bf16(aF[m], bF[n], acc[m][n], 0, 0, 0);
    }
    __syncthreads();
  }

  const int rbase = tile_m + wm * 64 + l4 * 4;
  const int cbase = tile_n + wn * 64 + l15;
  if constexpr (EPI == 5) {
    const float* bias = (const float*)extra;
    #pragma unroll
    for (int m = 0; m < 4; ++m) {
      int row0 = rbase + m * 16;
      int bb = row0 >> 11, s0 = row0 & 2047;
      #pragma unroll
      for (int n = 0; n < 4; ++n) {
        int col = cbase + n * 16;
        if (col < 512) {
          #pragma unroll
          for (int j = 0; j < 4; ++j)
            ((bf16_t*)Cout)[(size_t)(row0 + j) * 2048 + col] = (bf16_t)acc[m][n][j];
        } else if (col < 1024) {
          int hd = col - 512;
          bf16x4 pk;
          #pragma unroll
          for (int j = 0; j < 4; ++j) {
            bf16_t bv = (bf16_t)acc[m][n][j];
            ((bf16_t*)Cout)[(size_t)(row0 + j) * 2048 + col] = bv;
            pk[j] = bv;
          }
          *(bf16x4*)(kTg + ((size_t)(bb * 8 + (hd >> 6)) * 64 + (hd & 63)) * Ssz + s0) = pk;
        } else if (col < 1536) {
          int hd = col - 1024;
          bf16x4 pv;
          #pragma unroll
          for (int j = 0; j < 4; ++j) pv[j] = (bf16_t)acc[m][n][j];
          *(bf16x4*)(vTg + ((size_t)(bb * 8 + (hd >> 6)) * 64 + (hd & 63)) * Ssz + s0) = pv;
        } else {
          float b = bias[col - 1536];
          #pragma unroll
          for (int j = 0; j < 4; ++j) {
            float z = acc[m][n][j] + b;
            ((bf16_t*)Cout)[(size_t)(row0 + j) * 2048 + col] = (bf16_t)(1.f / (1.f + __expf(-z)));
          }
        }
      }
    }
  } else {  /* EPI == 3 */
    #pragma unroll
    for (int m = 0; m < 4; ++m)
      #pragma unroll
      for (int n = 0; n < 4; ++n)
        #pragma unroll
        for (int j = 0; j < 4; ++j) {
          int row = rbase + m * 16 + j;
          int col = cbase + n * 16;
          ((float*)Cout)[(size_t)row * N + col] =
              acc[m][n][j] + ((const float*)extra)[(size_t)row * N + col];
        }
  }
}

/* ---------------- gates pass A ---------------- */
__global__ __launch_bounds__(64) void gates_a(const float* __restrict__ ifb,
                                              float* __restrict__ blocal,
                                              float* __restrict__ Mhat) {
  int bh = blockIdx.x >> 5, c = blockIdx.x & 31;
  int b = bh >> 3, h = bh & 7;
  int lane = threadIdx.x;
  size_t tok = (size_t)b * Ssz + c * Lc + lane;
  float iv = ifb[tok * 16 + h];
  float fv = ifb[tok * 16 + 8 + h];
  float bt = fv;
  #pragma unroll
  for (int d = 1; d < 64; d <<= 1) { float o = __shfl_up(bt, d, 64); if (lane >= d) bt += o; }
  float a = iv - bt;
  float pm = a;
  #pragma unroll
  for (int d = 1; d < 64; d <<= 1) { float o = __shfl_up(pm, d, 64); if (lane >= d) pm = fmaxf(pm, o); }
  blocal[(size_t)bh * Ssz + c * Lc + lane] = bt;
  Mhat[(size_t)bh * Ssz + c * Lc + lane] = bt + pm;
}

/* ---------------- gates pass B ---------------- */
__global__ void gates_b(const float* __restrict__ blocal, const float* __restrict__ Mhat,
                        float* __restrict__ mstart, float* __restrict__ decays,
                        float* __restrict__ mend) {
  int bh = threadIdx.x;
  if (bh < NBH) {
    float M = 0.f;
    for (int c = 0; c < NCH; ++c) {
      mstart[bh * NCH + c] = M;
      float bL = blocal[(size_t)bh * Ssz + c * Lc + 63];
      float Mh = Mhat[(size_t)bh * Ssz + c * Lc + 63];
      float Mn = fmaxf(M + bL, Mh);
      decays[bh * NCH + c] = __expf(M + bL - Mn);
      mend[bh * NCH + c] = Mn;
      M = Mn;
    }
  }
}

/* ---------------- per-chunk state increment, MFMA ---------------- */
__global__ __launch_bounds__(256) void chunk_inc_mfma(const bf16_t* __restrict__ kTg,
                                                      const bf16_t* __restrict__ vTg,
                                                      const float* __restrict__ ifb,
                                                      const float* __restrict__ blocal,
                                                      const float* __restrict__ mend,
                                                      bf16_t* __restrict__ G,
                                                      float* __restrict__ ng) {
  int bh = blockIdx.x >> 5, c = blockIdx.x & 31;
  int b = bh >> 3, h = bh & 7;
  __shared__ bf16_t Vt[64 * 64];
  __shared__ bf16_t Kw[64 * 64];
  __shared__ float wsh[64];
  const int t = threadIdx.x, w = t >> 6, l = t & 63;
  const int l15 = l & 15, l4 = l >> 4;
  if (t < 64) {
    float mL = mend[bh * NCH + c];
    float bL = blocal[(size_t)bh * Ssz + c * Lc + 63];
    float bt = blocal[(size_t)bh * Ssz + c * Lc + t];
    float iv = ifb[((size_t)b * Ssz + c * Lc + t) * 16 + h];
    wsh[t] = __expf(iv + bL - bt - mL);
  }
  __syncthreads();
  {
    const int r = l >> 3, c8 = (l & 7) * 8;
    #pragma unroll
    for (int i = 0; i < 2; ++i) {
      int seg = w * 2 + i, row = seg * 8 + r;
      gload16(vTg + ((size_t)bh * 64 + row) * Ssz + c * 64 + c8, &Vt[seg * 512]);
    }
    #pragma unroll
    for (int i = 0; i < 2; ++i) {
      int e = t + i * 256; int row = e >> 3, c0 = (e & 7) * 8;
      bf16x8 kv = *(const bf16x8*)(kTg + ((size_t)bh * 64 + row) * Ssz + c * 64 + c0);
      #pragma unroll
      for (int j = 0; j < 8; ++j) kv[j] = (bf16_t)((float)kv[j] * wsh[c0 + j]);
      *(bf16x8*)&Kw[row * 64 + c0] = kv;
    }
  }
  __syncthreads();
  f32x4 acc[4];
  #pragma unroll
  for (int n = 0; n < 4; ++n) acc[n] = (f32x4){0.f, 0.f, 0.f, 0.f};
  #pragma unroll
  for (int kk = 0; kk < 2; ++kk) {
    bf16x8 af = *(const bf16x8*)&Vt[(w * 16 + l15) * 64 + kk * 32 + l4 * 8];
    #pragma unroll
    for (int n = 0; n < 4; ++n) {
      bf16x8 bfr = *(const bf16x8*)&Kw[(n * 16 + l15) * 64 + kk * 32 + l4 * 8];
      acc[n] = __builtin_amdgcn_mfma_f32_16x16x32_bf16(af, bfr, acc[n], 0, 0, 0);
    }
  }
  size_t gb = ((size_t)bh * NCH + c) * 4096;
  #pragma unroll
  for (int n = 0; n < 4; ++n)
    #pragma unroll
    for (int j = 0; j < 4; ++j) {
      int row = w * 16 + l4 * 4 + j;
      int col = n * 16 + l15;
      G[gb + (size_t)row * 64 + col] = (bf16_t)acc[n][j];
    }
  if (t < 64) {
    float s = 0.f;
    for (int s2 = 0; s2 < 64; ++s2) s += (float)Kw[t * 64 + s2];
    ng[((size_t)bh * NCH + c) * 64 + t] = s;
  }
}

/* ---------------- state scan ---------------- */
__global__ __launch_bounds__(256) void state_scan(const bf16_t* __restrict__ G,
                                                  const float* __restrict__ ng,
                                                  const float* __restrict__ decays,
                                                  bf16_t* __restrict__ CstB,
                                                  float* __restrict__ nst) {
  int gid = blockIdx.x;
  if (gid < 512) {
    int idx = gid * 256 + threadIdx.x;
    int bh = idx >> 12, e = idx & 4095;
    const float* d = decays + bh * NCH;
    float C = 0.f;
    #pragma unroll
    for (int c = 0; c < NCH; ++c) {
      size_t o = ((size_t)bh * NCH + c) * 4096 + e;
      CstB[o] = (bf16_t)C;
      C = d[c] * C + (float)G[o];
    }
  } else {
    int idx = (gid - 512) * 256 + threadIdx.x;
    int bh = idx >> 6, e = idx & 63;
    const float* d = decays + bh * NCH;
    float n = 0.f;
    #pragma unroll
    for (int c = 0; c < NCH; ++c) {
      size_t o = ((size_t)bh * NCH + c) * 64 + e;
      nst[o] = n;
      n = d[c] * n + ng[o];
    }
  }
}

/* ---------------- intra-chunk outputs + fused group-norm/out-gate ---------------- */
__global__ __launch_bounds__(256) void intra_mfma(const bf16_t* __restrict__ qkvo,
                                                  const bf16_t* __restrict__ vTg,
                                                  const bf16_t* __restrict__ CstB,
                                                  const float* __restrict__ nst,
                                                  const float* __restrict__ ifb,
                                                  const float* __restrict__ blocal,
                                                  const float* __restrict__ Mhat,
                                                  const float* __restrict__ mstart,
                                                  const float* __restrict__ mhg,
                                                  bf16_t* __restrict__ gated) {
  int bh = blockIdx.x >> 5, c = blockIdx.x & 31;
  int b = bh >> 3, h = bh & 7;
  __shared__ bf16_t qs[64 * 64];
  __shared__ bf16_t ks[64 * 64];
  __shared__ bf16_t vTs[64 * 64];
  __shared__ bf16_t Cs[64 * 64];
  __shared__ float nin[64], den_s[64], ssrc[64], sdst[64], esc[64];
  const int t = threadIdx.x, w = t >> 6, l = t & 63;
  const int l15 = l & 15, l4 = l >> 4;
  const size_t tok0 = (size_t)b * Ssz + c * Lc;
  const size_t cbase = ((size_t)bh * NCH + c) * 4096;

  if (t < 64) {
    nin[t] = nst[((size_t)bh * NCH + c) * 64 + t];
    float bt = blocal[(size_t)bh * Ssz + c * Lc + t];
    float Mh2 = Mhat[(size_t)bh * Ssz + c * Lc + t];
    float Mc = mstart[bh * NCH + c];
    float iv = ifb[(tok0 + t) * 16 + h];
    float mt = fmaxf(Mc + bt, Mh2);
    ssrc[t] = iv - bt;
    sdst[t] = bt - mt;
    esc[t]  = __expf(Mc + bt - mt);
  }
  {
    const int r = l >> 3, c8 = (l & 7) * 8;
    #pragma unroll
    for (int i = 0; i < 2; ++i) {
      int seg = w * 2 + i, row = seg * 8 + r;
      gload16(qkvo + (tok0 + row) * 2048 + h * 64 + c8,          &qs[seg * 512]);
      gload16(qkvo + (tok0 + row) * 2048 + 512 + h * 64 + c8,    &ks[seg * 512]);
      gload16(vTg + ((size_t)bh * 64 + row) * Ssz + c * 64 + c8, &vTs[seg * 512]);
      gload16(CstB + cbase + seg * 512 + l * 8,                  &Cs[seg * 512]);
    }
  }
  __syncthreads();

  f32x4 aS[4];
  #pragma unroll
  for (int n = 0; n < 4; ++n) aS[n] = (f32x4){0.f, 0.f, 0.f, 0.f};
  #pragma unroll
  for (int kk = 0; kk < 2; ++kk) {
    bf16x8 af = *(const bf16x8*)&qs[(w * 16 + l15) * 64 + kk * 32 + l4 * 8];
    #pragma unroll
    for (int n = 0; n < 4; ++n) {
      bf16x8 bfr = *(const bf16x8*)&ks[(n * 16 + l15) * 64 + kk * 32 + l4 * 8];
      aS[n] = __builtin_amdgcn_mfma_f32_16x16x32_bf16(af, bfr, aS[n], 0, 0, 0);
    }
  }
  {
    int row = w * 16 + (l >> 2);
    int c0 = (l & 3) * 16;
    float e = esc[row];
    #pragma unroll
    for (int i2 = 0; i2 < 2; ++i2) {
      bf16x8 v8 = *(const bf16x8*)&qs[row * 64 + c0 + i2 * 8];
      #pragma unroll
      for (int j = 0; j < 8; ++j) v8[j] = (bf16_t)((float)v8[j] * e);
      *(bf16x8*)&qs[row * 64 + c0 + i2 * 8] = v8;
    }
  }
  float rs[4] = {0.f, 0.f, 0.f, 0.f};
  #pragma unroll
  for (int n = 0; n < 4; ++n) {
    int col = n * 16 + l15;
    float es = ssrc[col];
    #pragma unroll
    for (int j = 0; j < 4; ++j) {
      int row = w * 16 + l4 * 4 + j;
      float p = (col <= row) ? aS[n][j] * __expf(es + sdst[row]) : 0.f;
      aS[n][j] = p;
      rs[j] += p;
    }
  }
  #pragma unroll
  for (int j = 0; j < 4; ++j) {
    rs[j] += __shfl_xor(rs[j], 1, 64);
    rs[j] += __shfl_xor(rs[j], 2, 64);
    rs[j] += __shfl_xor(rs[j], 4, 64);
    rs[j] += __shfl_xor(rs[j], 8, 64);
  }
  if (l15 == 0) {
    #pragma unroll
    for (int j = 0; j < 4; ++j) den_s[w * 16 + l4 * 4 + j] = rs[j];
  }
  __syncthreads();

  #pragma unroll
  for (int n = 0; n < 4; ++n)
    #pragma unroll
    for (int j = 0; j < 4; ++j)
      ks[(w * 16 + l4 * 4 + j) * 64 + n * 16 + l15] = (bf16_t)aS[n][j];

  {
    int row = w * 16 + (l >> 2);
    int c0 = (l & 3) * 16;
    float part = 0.f;
    #pragma unroll
    for (int i2 = 0; i2 < 16; ++i2)
      part += (float)qs[row * 64 + c0 + i2] * nin[c0 + i2];
    part += __shfl_xor(part, 1, 64);
    part += __shfl_xor(part, 2, 64);
    if ((l & 3) == 0)
      den_s[row] = fmaxf(fabsf(den_s[row] + part), 1.0f);
  }
  __syncthreads();

  f32x4 aO[4];
  #pragma unroll
  for (int n = 0; n < 4; ++n) aO[n] = (f32x4){0.f, 0.f, 0.f, 0.f};
  #pragma unroll
  for (int kk = 0; kk < 2; ++kk) {
    bf16x8 afP = *(const bf16x8*)&ks[(w * 16 + l15) * 64 + kk * 32 + l4 * 8];
    bf16x8 afQ = *(const bf16x8*)&qs[(w * 16 + l15) * 64 + kk * 32 + l4 * 8];
    #pragma unroll
    for (int n = 0; n < 4; ++n) {
      bf16x8 bV = *(const bf16x8*)&vTs[(n * 16 + l15) * 64 + kk * 32 + l4 * 8];
      bf16x8 bC = *(const bf16x8*)&Cs[(n * 16 + l15) * 64 + kk * 32 + l4 * 8];
      aO[n] = __builtin_amdgcn_mfma_f32_16x16x32_bf16(afP, bV, aO[n], 0, 0, 0);
      aO[n] = __builtin_amdgcn_mfma_f32_16x16x32_bf16(afQ, bC, aO[n], 0, 0, 0);
    }
  }

  #pragma unroll
  for (int j = 0; j < 4; ++j) {
    int row = w * 16 + l4 * 4 + j;
    float rinv = 1.f / den_s[row];
    float ov[4];
    #pragma unroll
    for (int n = 0; n < 4; ++n) ov[n] = aO[n][j] * rinv;
    float s = ov[0] + ov[1] + ov[2] + ov[3];
    s += __shfl_xor(s, 1, 64); s += __shfl_xor(s, 2, 64);
    s += __shfl_xor(s, 4, 64); s += __shfl_xor(s, 8, 64);
    float mu = s * (1.f / 64.f);
    float s2 = 0.f;
    #pragma unroll
    for (int n = 0; n < 4; ++n) { float d = ov[n] - mu; s2 += d * d; }
    s2 += __shfl_xor(s2, 1, 64); s2 += __shfl_xor(s2, 2, 64);
    s2 += __shfl_xor(s2, 4, 64); s2 += __shfl_xor(s2, 8, 64);
    float rstd = rsqrtf(s2 * (1.f / 64.f) + 1e-5f);
    size_t tok = tok0 + row;
    #pragma unroll
    for (int n = 0; n < 4; ++n) {
      int colh = n * 16 + l15;
      float og = (float)qkvo[tok * 2048 + 1536 + h * 64 + colh];
      float hn = (ov[n] - mu) * rstd * mhg[h * 64 + colh];
      gated[tok * 512 + h * 64 + colh] = (bf16_t)(og * hn);
    }
  }
}

/* ---------------- launcher ---------------- */
extern "C" void kernel_launch(void* const* d_in, const int* in_sizes, int n_in,
                              void* d_out, int out_size, void* d_ws, size_t ws_size,
                              hipStream_t stream) {
  const float* x     = (const float*)d_in[0];
  const float* ln_g  = (const float*)d_in[1];
  const float* ln_b  = (const float*)d_in[2];
  const float* W_up  = (const float*)d_in[3];
  const float* W_down= (const float*)d_in[4];
  const float* Wq    = (const float*)d_in[5];
  const float* Wk    = (const float*)d_in[6];
  const float* Wv    = (const float*)d_in[7];
  const float* Wi    = (const float*)d_in[8];
  const float* bi    = (const float*)d_in[9];
  const float* Wf    = (const float*)d_in[10];
  const float* bfv   = (const float*)d_in[11];
  const float* Wo    = (const float*)d_in[12];
  const float* bo    = (const float*)d_in[13];
  const float* mh_g  = (const float*)d_in[14];
  const float* W_out = (const float*)d_in[15];

  char* ws = (char*)d_ws;
  bf16_t* hbuf   = (bf16_t*)(ws + OFF_H);
  bf16_t* wqxT   = (bf16_t*)(ws + OFF_WQX);
  bf16_t* wqcT   = (bf16_t*)(ws + OFF_WQC);
  bf16_t* wdownT = (bf16_t*)(ws + OFF_WDOWNT);
  bf16_t* wocT   = (bf16_t*)(ws + OFF_WOC);
  bf16_t* wupB   = (bf16_t*)(ws + OFF_WUPB);
  bf16_t* wuifT  = (bf16_t*)(ws + OFF_WUIF);
  float*  biasA  = (float*)(ws + OFF_BIAS);
  bf16_t* woutB  = (bf16_t*)(ws + OFF_WOUTB);
  bf16_t* qkvob  = (bf16_t*)(ws + OFF_QKVO);
  bf16_t* kTg    = (bf16_t*)(ws + OFF_KT);
  bf16_t* vTg    = (bf16_t*)(ws + OFF_VT);
  bf16_t* gbuf   = (bf16_t*)(ws + OFF_GATED);
  bf16_t* Gbuf   = (bf16_t*)(ws + OFF_G);
  float*  ifb    = (float*)(ws + OFF_IFB);
  float*  bloc   = (float*)(ws + OFF_BLOC);
  float*  Mh     = (float*)(ws + OFF_MHAT);
  float*  mst    = (float*)(ws + OFF_MST);
  float*  decays = (float*)(ws + OFF_DEC);
  float*  mendb  = (float*)(ws + OFF_MEND);
  float*  ngbuf  = (float*)(ws + OFF_NG);
  float*  nst    = (float*)(ws + OFF_NST);
  float*  wocP   = (float*)(ws + OFF_WOCP);
  float*  compP  = (float*)(ws + OFF_COMPP);
  bf16_t* CstB   = (bf16_t*)(ws + OFF_CSTB);

  prep_weights<<<6145, dim3(32, 8), 0, stream>>>(W_up, Wq, Wk, Wv, Wo, W_down, W_out,
                                                 bo, bi, bfv, wqxT, wdownT, woutB, wupB, biasA);
  build_wuif<<<Dsz, 64, 0, stream>>>(W_up, Wi, Wf, wuifT);

  /* composite Wqc^T(2048,768) = wqxT(2048,1536) @ wupB(768,1536)^T, split-K x4 */
  gemm_partk<<<dim3(6, 16, 4), 256, 0, stream>>>(wqxT, wupB, compP, 2048, 768, 1536, 384);
  partk_reduce<<<6144, 256, 0, stream>>>(compP, wqcT, 2048 * 768, 4);
  /* WocT(768,512) = wdownT @ woutB^T, split-K x8 */
  gemm_partk<<<dim3(4, 6, 8), 256, 0, stream>>>(wdownT, woutB, wocP, 768, 512, 1536, 192);
  partk_reduce<<<1536, 256, 0, stream>>>(wocP, wocT, 768 * 512, 8);

  ln_kernel<<<NTOK, 256, 0, stream>>>(x, ln_g, ln_b, hbuf);
  ifproj_mfma<<<NTOK / 128, 256, 0, stream>>>(hbuf, wuifT, bi, bfv, ifb);

  /* fused qkvo' = h @ Wqc (K=768) + kv-transpose + sigmoid(o); grid 512 */
  gemm_mn<5><<<dim3(2048 / 128, NTOK / 256), 512, 0, stream>>>(hbuf, wqcT, qkvob, biasA, kTg, vTg, NTOK, 2048, Dsz);

  gates_a<<<NBH * NCH, 64, 0, stream>>>(ifb, bloc, Mh);
  gates_b<<<1, 32, 0, stream>>>(bloc, Mh, mst, decays, mendb);
  chunk_inc_mfma<<<NBH * NCH, 256, 0, stream>>>(kTg, vTg, ifb, bloc, mendb, Gbuf, ngbuf);
  state_scan<<<520, 256, 0, stream>>>(Gbuf, ngbuf, decays, CstB, nst);
  intra_mfma<<<NBH * NCH, 256, 0, stream>>>(qkvob, vTg, CstB, nst, ifb, bloc, Mh, mst, mh_g, gbuf);

  /* fused: out = x + gated @ (W_out @ W_down), K=512 */
  gemm_mn<3><<<dim3(Dsz / 128, NTOK / 256), 512, 0, stream>>>(gbuf, wocT, (float*)d_out, x, nullptr, nullptr, NTOK, Dsz, 512);
}

// Round 14
// 157.499 us; speedup vs baseline: 1.4807x; 1.0362x over previous
//
#include <hip/hip_runtime.h>
#include <hip/hip_bf16.h>
#include <stdint.h>
#include <stddef.h>

typedef __bf16 bf16_t;
typedef __bf16 bf16x4 __attribute__((ext_vector_type(4)));
typedef __bf16 bf16x8 __attribute__((ext_vector_type(8)));
typedef float  f32x4  __attribute__((ext_vector_type(4)));

#define Bsz  4
#define Ssz  2048
#define Dsz  768
#define Isz  1536
#define Hn   8
#define HDsz 64
#define NTOK (Bsz*Ssz)      /* 8192 */
#define Lc   64
#define NCH  (Ssz/Lc)       /* 32 */
#define NBH  (Bsz*Hn)       /* 32 */

/* ---------------- workspace layout (bytes) ---------------- */
#define OFF_H      ((size_t)0)                    /* 12.58M; wocP & CstB alias */
#define OFF_WQX    ((size_t)12582912)             /* 2048x1536 bf16 = 6.29M */
#define OFF_WQC    ((size_t)18874368)             /* 2048x768 bf16 = 3.15M */
#define OFF_WDOWNT ((size_t)22020096)             /* 2.36M */
#define OFF_WOC    ((size_t)24379392)             /* 768x512 bf16 = 0.79M */
#define OFF_WUPB   ((size_t)25165824)             /* 768x1536 bf16 = 2.36M */
#define OFF_WUIF   ((size_t)27525120)             /* 16x768 bf16 = 24.6K */
#define OFF_BIAS   ((size_t)27549696)             /* 528 f32, pad 4K */
#define OFF_WOUTB  ((size_t)27553792)             /* 512x1536 bf16 = 1.57M */
#define OFF_QKVO   ((size_t)29126656)             /* 8192x2048 bf16 = 33.55M */
#define OFF_KT     ((size_t)62681088)             /* 8.39M */
#define OFF_VT     ((size_t)71069696)             /* 8.39M */
#define OFF_GATED  ((size_t)79458304)             /* 8.39M */
#define OFF_G      ((size_t)87846912)             /* 8.39M */
#define OFF_IFB    ((size_t)96235520)             /* 0.52M */
#define OFF_BLOC   ((size_t)96759808)
#define OFF_MHAT   ((size_t)97021952)
#define OFF_MST    ((size_t)97284096)
#define OFF_DEC    ((size_t)97288192)
#define OFF_MEND   ((size_t)97292288)
#define OFF_NG     ((size_t)97296384)
#define OFF_NST    ((size_t)97558528)             /* end 97820672 */
/* aliases (dead before region overwritten) */
#define OFF_WOCP   OFF_H                          /* 8x768x512 f32 = 12.58M, dead before ln */
#define OFF_CSTB   OFF_H                          /* 8.39M, after qkvo-gemm (h dead) */
#define OFF_COMPP  OFF_QKVO                       /* 4x2048x768 f32 = 25.2M, dead before qkvo write */

/* ---------------- helpers ---------------- */
__device__ __forceinline__ void gload16(const void* gsrc, void* ldst) {
  __builtin_amdgcn_global_load_lds(
      (const __attribute__((address_space(1))) void*)gsrc,
      (__attribute__((address_space(3))) void*)ldst, 16, 0, 0);
}

__device__ __forceinline__ float blockReduceSum256(float v) {
  #pragma unroll
  for (int o = 1; o < 64; o <<= 1) v += __shfl_xor(v, o, 64);
  __shared__ float sh[4];
  int wid = threadIdx.x >> 6;
  __syncthreads();
  if ((threadIdx.x & 63) == 0) sh[wid] = v;
  __syncthreads();
  return sh[0] + sh[1] + sh[2] + sh[3];
}

/* ======================================================================
   prep_weights — all transposes/casts/bias/Wuif in ONE kernel. grid 6337:
     [0,768)      Wq  -> wqxT          [768,1536)  Wk*0.125
     [1536,2304)  Wv                    [2304,3072) Wo
     [3072,4224)  W_down -> wdownT
     [4224,4992)  W_out cast -> woutB   [4992,6144) W_up cast -> wupB
     [6144,6336)  Wuif composite (f32): 4 d-rows/block, 1 wave each
     [6336]       bias pack [bo, bi, bf]
   ====================================================================== */
__global__ __launch_bounds__(256) void prep_weights(
    const float* __restrict__ W_up, const float* __restrict__ Wq,
    const float* __restrict__ Wk, const float* __restrict__ Wv,
    const float* __restrict__ Wo, const float* __restrict__ W_down,
    const float* __restrict__ W_out, const float* __restrict__ Wi,
    const float* __restrict__ Wf, const float* __restrict__ bo,
    const float* __restrict__ bi, const float* __restrict__ bfv,
    bf16_t* __restrict__ wqxT, bf16_t* __restrict__ wdownT,
    bf16_t* __restrict__ woutB, bf16_t* __restrict__ wupB,
    bf16_t* __restrict__ wuifT, float* __restrict__ biasA) {
  __shared__ float tile[32][33];
  const int bid = blockIdx.x;
  const int tx = threadIdx.x, ty = threadIdx.y;
  const int tid = ty * 32 + tx;
  const float* src; bf16_t* dst; int K, N, bx, by; float scale = 1.f;
  if (bid < 768)       { int l = bid;        src = Wq;     dst = wqxT;                      K = 1536; N = 512; bx = l % 16; by = l / 16; }
  else if (bid < 1536) { int l = bid - 768;  src = Wk;     dst = wqxT + (size_t)512 * Isz;  K = 1536; N = 512; bx = l % 16; by = l / 16; scale = 0.125f; }
  else if (bid < 2304) { int l = bid - 1536; src = Wv;     dst = wqxT + (size_t)1024 * Isz; K = 1536; N = 512; bx = l % 16; by = l / 16; }
  else if (bid < 3072) { int l = bid - 2304; src = Wo;     dst = wqxT + (size_t)1536 * Isz; K = 1536; N = 512; bx = l % 16; by = l / 16; }
  else if (bid < 4224) { int l = bid - 3072; src = W_down; dst = wdownT;                    K = 1536; N = 768; bx = l % 24; by = l / 24; }
  else if (bid < 4992) {
    int base = (bid - 4224) * 1024 + tid * 4;
    #pragma unroll
    for (int e = 0; e < 4; ++e) woutB[base + e] = (bf16_t)W_out[base + e];
    return;
  } else if (bid < 6144) {
    int base = (bid - 4992) * 1024 + tid * 4;
    #pragma unroll
    for (int e = 0; e < 4; ++e) wupB[base + e] = (bf16_t)W_up[base + e];
    return;
  } else if (bid < 6336) {
    /* Wuif composite = W_up @ [Wi|Wf], f32 accumulation; 4 d's/block */
    int sub = tid >> 6, lane = tid & 63;
    int d = (bid - 6144) * 4 + sub;
    float acc[16];
    #pragma unroll
    for (int j = 0; j < 16; ++j) acc[j] = 0.f;
    for (int i = lane; i < Isz; i += 64) {
      float w = W_up[(size_t)d * Isz + i];
      f32x4 wi0 = *(const f32x4*)&Wi[(size_t)i * 8];
      f32x4 wi1 = *(const f32x4*)&Wi[(size_t)i * 8 + 4];
      f32x4 wf0 = *(const f32x4*)&Wf[(size_t)i * 8];
      f32x4 wf1 = *(const f32x4*)&Wf[(size_t)i * 8 + 4];
      #pragma unroll
      for (int j = 0; j < 4; ++j) {
        acc[j]      += w * wi0[j];
        acc[4 + j]  += w * wi1[j];
        acc[8 + j]  += w * wf0[j];
        acc[12 + j] += w * wf1[j];
      }
    }
    #pragma unroll
    for (int j = 0; j < 16; ++j)
      #pragma unroll
      for (int o = 1; o < 64; o <<= 1) acc[j] += __shfl_xor(acc[j], o, 64);
    if (lane == 0) {
      #pragma unroll
      for (int j = 0; j < 16; ++j)
        wuifT[(size_t)j * Dsz + d] = (bf16_t)acc[j];
    }
    return;
  } else {
    for (int i = tid; i < 528; i += 256)
      biasA[i] = (i < 512) ? bo[i] : ((i < 520) ? bi[i - 512] : bfv[i - 520]);
    return;
  }
  int n0 = bx * 32, k0 = by * 32;
  #pragma unroll
  for (int j = 0; j < 32; j += 8)
    tile[ty + j][tx] = src[(size_t)(k0 + ty + j) * N + n0 + tx];
  __syncthreads();
  #pragma unroll
  for (int j = 0; j < 32; j += 8)
    dst[(size_t)(n0 + ty + j) * K + k0 + tx] = (bf16_t)(tile[tx][ty + j] * scale);
}

/* ---------------- merged split-K precompute GEMMs (comp 384 blks + woc 192) ---------------- */
__global__ __launch_bounds__(256) void gemm_partk2(const bf16_t* __restrict__ wqxT,
                                                   const bf16_t* __restrict__ wupB,
                                                   float* __restrict__ compP,
                                                   const bf16_t* __restrict__ wdownT,
                                                   const bf16_t* __restrict__ woutB,
                                                   float* __restrict__ wocP) {
  const bf16_t *A, *Bt; float* P;
  int M, N, Ktot, kslice, bx, by, kz;
  int bid = blockIdx.x;
  if (bid < 384) {          /* Wqc: M=2048 N=768 K=1536, z=4 */
    A = wqxT; Bt = wupB; P = compP;
    M = 2048; N = 768; Ktot = 1536; kslice = 384;
    kz = bid / 96; int r = bid % 96; by = r / 6; bx = r % 6;
  } else {                  /* Woc: M=768 N=512 K=1536, z=8 */
    int l = bid - 384;
    A = wdownT; Bt = woutB; P = wocP;
    M = 768; N = 512; Ktot = 1536; kslice = 192;
    kz = l / 24; int r = l % 24; by = r / 4; bx = r % 4;
  }
  __shared__ bf16_t As[128 * 64];
  __shared__ bf16_t Bs[128 * 64];
  const int t = threadIdx.x;
  const int w = t >> 6, l = t & 63;
  const int tile_m = by * 128, tile_n = bx * 128;
  const int wr = w >> 1, wc = w & 1;
  const int lrow = l >> 3;
  const int lks = ((l & 7) * 8) ^ (lrow << 3);
  const int l15 = l & 15, l4 = l >> 4;

  f32x4 acc[4][4];
  #pragma unroll
  for (int m = 0; m < 4; ++m)
    #pragma unroll
    for (int n = 0; n < 4; ++n) acc[m][n] = (f32x4){0.f, 0.f, 0.f, 0.f};

  for (int k0 = kz * kslice; k0 < kz * kslice + kslice; k0 += 64) {
    #pragma unroll
    for (int i = 0; i < 4; ++i) {
      int ch = w * 4 + i;
      int row = ch * 8 + lrow;
      gload16(A  + (size_t)(tile_m + row) * Ktot + k0 + lks, &As[ch * 512]);
      gload16(Bt + (size_t)(tile_n + row) * Ktot + k0 + lks, &Bs[ch * 512]);
    }
    __syncthreads();
    #pragma unroll
    for (int kk = 0; kk < 2; ++kk) {
      bf16x8 af[4], bfr[4];
      #pragma unroll
      for (int m = 0; m < 4; ++m) {
        int r = wr * 64 + m * 16 + l15;
        af[m] = *(const bf16x8*)&As[r * 64 + ((kk * 32 + l4 * 8) ^ ((r & 7) << 3))];
      }
      #pragma unroll
      for (int n = 0; n < 4; ++n) {
        int r = wc * 64 + n * 16 + l15;
        bfr[n] = *(const bf16x8*)&Bs[r * 64 + ((kk * 32 + l4 * 8) ^ ((r & 7) << 3))];
      }
      #pragma unroll
      for (int m = 0; m < 4; ++m)
        #pragma unroll
        for (int n = 0; n < 4; ++n)
          acc[m][n] = __builtin_amdgcn_mfma_f32_16x16x32_bf16(af[m], bfr[n], acc[m][n], 0, 0, 0);
    }
    __syncthreads();
  }

  const int rbase = tile_m + wr * 64 + l4 * 4;
  const int cbase = tile_n + wc * 64 + l15;
  float* Pz = P + (size_t)kz * M * N;
  #pragma unroll
  for (int m = 0; m < 4; ++m)
    #pragma unroll
    for (int n = 0; n < 4; ++n)
      #pragma unroll
      for (int j = 0; j < 4; ++j)
        Pz[(size_t)(rbase + m * 16 + j) * N + cbase + n * 16] = acc[m][n][j];
}

/* ---------------- merged vectorized reductions (comp 1536 blks + woc 384) ---------------- */
__global__ __launch_bounds__(256) void reduce2(const float* __restrict__ compP,
                                               bf16_t* __restrict__ wqcT,
                                               const float* __restrict__ wocP,
                                               bf16_t* __restrict__ wocT) {
  int bid = blockIdx.x;
  const float* P; bf16_t* out; int nelem, nz, e;
  if (bid < 1536) { P = compP; out = wqcT; nelem = 2048 * 768; nz = 4; e = (bid * 256 + threadIdx.x) * 4; }
  else            { P = wocP;  out = wocT; nelem = 768 * 512;  nz = 8; e = ((bid - 1536) * 256 + threadIdx.x) * 4; }
  f32x4 s = {0.f, 0.f, 0.f, 0.f};
  for (int z = 0; z < nz; ++z) {
    f32x4 v = *(const f32x4*)&P[(size_t)z * nelem + e];
    s[0] += v[0]; s[1] += v[1]; s[2] += v[2]; s[3] += v[3];
  }
  bf16x4 ov;
  #pragma unroll
  for (int j = 0; j < 4; ++j) ov[j] = (bf16_t)s[j];
  *(bf16x4*)&out[e] = ov;
}

/* ---------------- LayerNorm ---------------- */
__global__ __launch_bounds__(256) void ln_kernel(const float* __restrict__ x,
                                                 const float* __restrict__ g,
                                                 const float* __restrict__ bta,
                                                 bf16_t* __restrict__ h) {
  size_t tok = blockIdx.x;
  const float* xr = x + tok * Dsz;
  int t = threadIdx.x;
  float v[3]; float s = 0.f;
  #pragma unroll
  for (int i = 0; i < 3; ++i) { v[i] = xr[t + 256 * i]; s += v[i]; }
  s = blockReduceSum256(s);
  float mu = s * (1.f / Dsz);
  float s2 = 0.f;
  #pragma unroll
  for (int i = 0; i < 3; ++i) { float d = v[i] - mu; s2 += d * d; }
  s2 = blockReduceSum256(s2);
  float rs = rsqrtf(s2 * (1.f / Dsz) + 1e-5f);
  #pragma unroll
  for (int i = 0; i < 3; ++i) {
    int col = t + 256 * i;
    h[tok * Dsz + col] = (bf16_t)((v[i] - mu) * rs * g[col] + bta[col]);
  }
}

/* ---------------- i/f gate projection: ifb = h @ Wuif + bias ---------------- */
__global__ __launch_bounds__(256) void ifproj_mfma(const bf16_t* __restrict__ h,
                                                   const bf16_t* __restrict__ wuifT,
                                                   const float* __restrict__ bi,
                                                   const float* __restrict__ bfv,
                                                   float* __restrict__ ifb) {
  __shared__ bf16_t As[128 * 64];
  __shared__ bf16_t Bs[16 * 64];
  const int t = threadIdx.x, w = t >> 6, l = t & 63;
  const int l15 = l & 15, l4 = l >> 4;
  const int lrow = l >> 3, lk = (l & 7) * 8;
  const int tile_m = blockIdx.x * 128;
  f32x4 acc[2];
  acc[0] = (f32x4){0.f, 0.f, 0.f, 0.f};
  acc[1] = (f32x4){0.f, 0.f, 0.f, 0.f};

  for (int k0 = 0; k0 < Dsz; k0 += 64) {
    #pragma unroll
    for (int i = 0; i < 4; ++i) {
      int ch = w * 4 + i;
      int row = ch * 8 + lrow;
      gload16(h + (size_t)(tile_m + row) * Dsz + k0 + lk, &As[ch * 512]);
    }
    if (t < 128) {
      int rr = t >> 3, c0 = (t & 7) * 8;
      *(bf16x8*)&Bs[rr * 64 + c0] = *(const bf16x8*)(wuifT + (size_t)rr * Dsz + k0 + c0);
    }
    __syncthreads();
    #pragma unroll
    for (int kk = 0; kk < 2; ++kk) {
      bf16x8 bfr = *(const bf16x8*)&Bs[l15 * 64 + kk * 32 + l4 * 8];
      #pragma unroll
      for (int m = 0; m < 2; ++m) {
        bf16x8 af = *(const bf16x8*)&As[(w * 32 + m * 16 + l15) * 64 + kk * 32 + l4 * 8];
        acc[m] = __builtin_amdgcn_mfma_f32_16x16x32_bf16(af, bfr, acc[m], 0, 0, 0);
      }
    }
    __syncthreads();
  }
  float bias = (l15 < 8) ? bi[l15] : bfv[l15 - 8];
  #pragma unroll
  for (int m = 0; m < 2; ++m)
    #pragma unroll
    for (int j = 0; j < 4; ++j) {
      int row = tile_m + w * 32 + m * 16 + l4 * 4 + j;
      ifb[(size_t)row * 16 + l15] = acc[m][j] + bias;
    }
}

/* ======================================================================
   256M x 128N m97-style GEMM (proven: launch_bounds(512,4), VGPR 60).
   EPI: 3 = f32 out + resid; 5 = qkvo epilogue (N=2048, K=768 composite).
   ====================================================================== */
template<int EPI>
__global__ __launch_bounds__(512, 4) void gemm_mn(const bf16_t* __restrict__ A,
                                                  const bf16_t* __restrict__ Bt,
                                                  void* __restrict__ Cout,
                                                  const void* __restrict__ extra,
                                                  bf16_t* __restrict__ kTg,
                                                  bf16_t* __restrict__ vTg,
                                                  int M, int N, int K) {
  __shared__ bf16_t As[256 * 64];
  __shared__ bf16_t Bs[128 * 64];
  const int t = threadIdx.x;
  const int w = t >> 6, l = t & 63;
  const int wm = w >> 1, wn = w & 1;
  const int l15 = l & 15, l4 = l >> 4;

  const int gx = gridDim.x;
  const int nwg = gx * gridDim.y;
  const int cpx = nwg >> 3;
  int bid = blockIdx.y * gx + blockIdx.x;
  int wg = (bid & 7) * cpx + (bid >> 3);
  const int tile_m = (wg / gx) * 256;
  const int tile_n = (wg % gx) * 128;

  f32x4 acc[4][4];
  #pragma unroll
  for (int m = 0; m < 4; ++m)
    #pragma unroll
    for (int n = 0; n < 4; ++n) acc[m][n] = (f32x4){0.f, 0.f, 0.f, 0.f};

  for (int k0 = 0; k0 < K; k0 += 64) {
    #pragma unroll
    for (int j = 0; j < 4; ++j) {
      int c = t + j * 512;
      int row = c >> 3;
      int ec = ((c & 7) * 8) ^ ((row & 7) << 3);
      gload16(A + (size_t)(tile_m + row) * K + k0 + ec, (char*)As + (size_t)c * 16);
    }
    #pragma unroll
    for (int j = 0; j < 2; ++j) {
      int c = t + j * 512;
      int row = c >> 3;
      int ec = ((c & 7) * 8) ^ ((row & 7) << 3);
      gload16(Bt + (size_t)(tile_n + row) * K + k0 + ec, (char*)Bs + (size_t)c * 16);
    }
    __syncthreads();
    #pragma unroll
    for (int kk = 0; kk < 2; ++kk) {
      bf16x8 aF[4], bF[4];
      #pragma unroll
      for (int m = 0; m < 4; ++m) {
        int r = wm * 64 + m * 16 + l15;
        aF[m] = *(const bf16x8*)((const char*)As + r * 128 + ((kk * 64 + l4 * 16) ^ ((r & 7) << 4)));
      }
      #pragma unroll
      for (int n = 0; n < 4; ++n) {
        int r = wn * 64 + n * 16 + l15;
        bF[n] = *(const bf16x8*)((const char*)Bs + r * 128 + ((kk * 64 + l4 * 16) ^ ((r & 7) << 4)));
      }
      #pragma unroll
      for (int m = 0; m < 4; ++m)
        #pragma unroll
        for (int n = 0; n < 4; ++n)
          acc[m][n] = __builtin_amdgcn_mfma_f32_16x16x32_bf16(aF[m], bF[n], acc[m][n], 0, 0, 0);
    }
    __syncthreads();
  }

  const int rbase = tile_m + wm * 64 + l4 * 4;
  const int cbase = tile_n + wn * 64 + l15;
  if constexpr (EPI == 5) {
    const float* bias = (const float*)extra;
    #pragma unroll
    for (int m = 0; m < 4; ++m) {
      int row0 = rbase + m * 16;
      int bb = row0 >> 11, s0 = row0 & 2047;
      #pragma unroll
      for (int n = 0; n < 4; ++n) {
        int col = cbase + n * 16;
        if (col < 512) {
          #pragma unroll
          for (int j = 0; j < 4; ++j)
            ((bf16_t*)Cout)[(size_t)(row0 + j) * 2048 + col] = (bf16_t)acc[m][n][j];
        } else if (col < 1024) {
          int hd = col - 512;
          bf16x4 pk;
          #pragma unroll
          for (int j = 0; j < 4; ++j) {
            bf16_t bv = (bf16_t)acc[m][n][j];
            ((bf16_t*)Cout)[(size_t)(row0 + j) * 2048 + col] = bv;
            pk[j] = bv;
          }
          *(bf16x4*)(kTg + ((size_t)(bb * 8 + (hd >> 6)) * 64 + (hd & 63)) * Ssz + s0) = pk;
        } else if (col < 1536) {
          int hd = col - 1024;
          bf16x4 pv;
          #pragma unroll
          for (int j = 0; j < 4; ++j) pv[j] = (bf16_t)acc[m][n][j];
          *(bf16x4*)(vTg + ((size_t)(bb * 8 + (hd >> 6)) * 64 + (hd & 63)) * Ssz + s0) = pv;
        } else {
          float b = bias[col - 1536];
          #pragma unroll
          for (int j = 0; j < 4; ++j) {
            float z = acc[m][n][j] + b;
            ((bf16_t*)Cout)[(size_t)(row0 + j) * 2048 + col] = (bf16_t)(1.f / (1.f + __expf(-z)));
          }
        }
      }
    }
  } else {  /* EPI == 3 */
    #pragma unroll
    for (int m = 0; m < 4; ++m)
      #pragma unroll
      for (int n = 0; n < 4; ++n)
        #pragma unroll
        for (int j = 0; j < 4; ++j) {
          int row = rbase + m * 16 + j;
          int col = cbase + n * 16;
          ((float*)Cout)[(size_t)row * N + col] =
              acc[m][n][j] + ((const float*)extra)[(size_t)row * N + col];
        }
  }
}

/* ---------------- fused gates: per-bh chunk scans + boundary recurrence ---------------- */
__global__ __launch_bounds__(256) void gates_fused(const float* __restrict__ ifb,
                                                   float* __restrict__ blocal,
                                                   float* __restrict__ Mhat,
                                                   float* __restrict__ mstart,
                                                   float* __restrict__ decays,
                                                   float* __restrict__ mend) {
  int bh = blockIdx.x;
  int b = bh >> 3, h = bh & 7;
  int wid = threadIdx.x >> 6, lane = threadIdx.x & 63;
  __shared__ float bL_s[32], Mh_s[32];
  for (int c = wid; c < NCH; c += 4) {
    size_t tok = (size_t)b * Ssz + c * Lc + lane;
    float iv = ifb[tok * 16 + h];
    float fv = ifb[tok * 16 + 8 + h];
    float bt = fv;
    #pragma unroll
    for (int d = 1; d < 64; d <<= 1) { float o = __shfl_up(bt, d, 64); if (lane >= d) bt += o; }
    float a = iv - bt;
    float pm = a;
    #pragma unroll
    for (int d = 1; d < 64; d <<= 1) { float o = __shfl_up(pm, d, 64); if (lane >= d) pm = fmaxf(pm, o); }
    blocal[(size_t)bh * Ssz + c * Lc + lane] = bt;
    Mhat[(size_t)bh * Ssz + c * Lc + lane] = bt + pm;
    if (lane == 63) { bL_s[c] = bt; Mh_s[c] = bt + pm; }
  }
  __syncthreads();
  if (threadIdx.x == 0) {
    float M = 0.f;
    for (int c = 0; c < NCH; ++c) {
      mstart[bh * NCH + c] = M;
      float Mn = fmaxf(M + bL_s[c], Mh_s[c]);
      decays[bh * NCH + c] = __expf(M + bL_s[c] - Mn);
      mend[bh * NCH + c] = Mn;
      M = Mn;
    }
  }
}

/* ---------------- per-chunk state increment, MFMA ---------------- */
__global__ __launch_bounds__(256) void chunk_inc_mfma(const bf16_t* __restrict__ kTg,
                                                      const bf16_t* __restrict__ vTg,
                                                      const float* __restrict__ ifb,
                                                      const float* __restrict__ blocal,
                                                      const float* __restrict__ mend,
                                                      bf16_t* __restrict__ G,
                                                      float* __restrict__ ng) {
  int bh = blockIdx.x >> 5, c = blockIdx.x & 31;
  int b = bh >> 3, h = bh & 7;
  __shared__ bf16_t Vt[64 * 64];
  __shared__ bf16_t Kw[64 * 64];
  __shared__ float wsh[64];
  const int t = threadIdx.x, w = t >> 6, l = t & 63;
  const int l15 = l & 15, l4 = l >> 4;
  if (t < 64) {
    float mL = mend[bh * NCH + c];
    float bL = blocal[(size_t)bh * Ssz + c * Lc + 63];
    float bt = blocal[(size_t)bh * Ssz + c * Lc + t];
    float iv = ifb[((size_t)b * Ssz + c * Lc + t) * 16 + h];
    wsh[t] = __expf(iv + bL - bt - mL);
  }
  __syncthreads();
  {
    const int r = l >> 3, c8 = (l & 7) * 8;
    #pragma unroll
    for (int i = 0; i < 2; ++i) {
      int seg = w * 2 + i, row = seg * 8 + r;
      gload16(vTg + ((size_t)bh * 64 + row) * Ssz + c * 64 + c8, &Vt[seg * 512]);
    }
    #pragma unroll
    for (int i = 0; i < 2; ++i) {
      int e = t + i * 256; int row = e >> 3, c0 = (e & 7) * 8;
      bf16x8 kv = *(const bf16x8*)(kTg + ((size_t)bh * 64 + row) * Ssz + c * 64 + c0);
      #pragma unroll
      for (int j = 0; j < 8; ++j) kv[j] = (bf16_t)((float)kv[j] * wsh[c0 + j]);
      *(bf16x8*)&Kw[row * 64 + c0] = kv;
    }
  }
  __syncthreads();
  f32x4 acc[4];
  #pragma unroll
  for (int n = 0; n < 4; ++n) acc[n] = (f32x4){0.f, 0.f, 0.f, 0.f};
  #pragma unroll
  for (int kk = 0; kk < 2; ++kk) {
    bf16x8 af = *(const bf16x8*)&Vt[(w * 16 + l15) * 64 + kk * 32 + l4 * 8];
    #pragma unroll
    for (int n = 0; n < 4; ++n) {
      bf16x8 bfr = *(const bf16x8*)&Kw[(n * 16 + l15) * 64 + kk * 32 + l4 * 8];
      acc[n] = __builtin_amdgcn_mfma_f32_16x16x32_bf16(af, bfr, acc[n], 0, 0, 0);
    }
  }
  size_t gb = ((size_t)bh * NCH + c) * 4096;
  #pragma unroll
  for (int n = 0; n < 4; ++n)
    #pragma unroll
    for (int j = 0; j < 4; ++j) {
      int row = w * 16 + l4 * 4 + j;
      int col = n * 16 + l15;
      G[gb + (size_t)row * 64 + col] = (bf16_t)acc[n][j];
    }
  if (t < 64) {
    float s = 0.f;
    for (int s2 = 0; s2 < 64; ++s2) s += (float)Kw[t * 64 + s2];
    ng[((size_t)bh * NCH + c) * 64 + t] = s;
  }
}

/* ---------------- state scan (vectorized C-path: bf16x4/thread) ---------------- */
__global__ __launch_bounds__(256) void state_scan(const bf16_t* __restrict__ G,
                                                  const float* __restrict__ ng,
                                                  const float* __restrict__ decays,
                                                  bf16_t* __restrict__ CstB,
                                                  float* __restrict__ nst) {
  int gid = blockIdx.x;
  if (gid < 128) {
    int e4 = (gid * 256 + threadIdx.x) * 4;    /* 131072 elems / 4 */
    int bh = e4 >> 12, e = e4 & 4095;
    const float* d = decays + bh * NCH;
    float C0 = 0.f, C1 = 0.f, C2 = 0.f, C3 = 0.f;
    #pragma unroll
    for (int c = 0; c < NCH; ++c) {
      size_t o = ((size_t)bh * NCH + c) * 4096 + e;
      bf16x4 st;
      st[0] = (bf16_t)C0; st[1] = (bf16_t)C1; st[2] = (bf16_t)C2; st[3] = (bf16_t)C3;
      *(bf16x4*)&CstB[o] = st;
      bf16x4 g4 = *(const bf16x4*)&G[o];
      float dc = d[c];
      C0 = dc * C0 + (float)g4[0];
      C1 = dc * C1 + (float)g4[1];
      C2 = dc * C2 + (float)g4[2];
      C3 = dc * C3 + (float)g4[3];
    }
  } else {
    int idx = (gid - 128) * 256 + threadIdx.x;  /* 2048 n-elems */
    int bh = idx >> 6, e = idx & 63;
    const float* d = decays + bh * NCH;
    float n = 0.f;
    #pragma unroll
    for (int c = 0; c < NCH; ++c) {
      size_t o = ((size_t)bh * NCH + c) * 64 + e;
      nst[o] = n;
      n = d[c] * n + ng[o];
    }
  }
}

/* ---------------- intra-chunk outputs + fused group-norm/out-gate ---------------- */
__global__ __launch_bounds__(256) void intra_mfma(const bf16_t* __restrict__ qkvo,
                                                  const bf16_t* __restrict__ vTg,
                                                  const bf16_t* __restrict__ CstB,
                                                  const float* __restrict__ nst,
                                                  const float* __restrict__ ifb,
                                                  const float* __restrict__ blocal,
                                                  const float* __restrict__ Mhat,
                                                  const float* __restrict__ mstart,
                                                  const float* __restrict__ mhg,
                                                  bf16_t* __restrict__ gated) {
  int bh = blockIdx.x >> 5, c = blockIdx.x & 31;
  int b = bh >> 3, h = bh & 7;
  __shared__ bf16_t qs[64 * 64];
  __shared__ bf16_t ks[64 * 64];
  __shared__ bf16_t vTs[64 * 64];
  __shared__ bf16_t Cs[64 * 64];
  __shared__ float nin[64], den_s[64], ssrc[64], sdst[64], esc[64];
  const int t = threadIdx.x, w = t >> 6, l = t & 63;
  const int l15 = l & 15, l4 = l >> 4;
  const size_t tok0 = (size_t)b * Ssz + c * Lc;
  const size_t cbase = ((size_t)bh * NCH + c) * 4096;

  if (t < 64) {
    nin[t] = nst[((size_t)bh * NCH + c) * 64 + t];
    float bt = blocal[(size_t)bh * Ssz + c * Lc + t];
    float Mh2 = Mhat[(size_t)bh * Ssz + c * Lc + t];
    float Mc = mstart[bh * NCH + c];
    float iv = ifb[(tok0 + t) * 16 + h];
    float mt = fmaxf(Mc + bt, Mh2);
    ssrc[t] = iv - bt;
    sdst[t] = bt - mt;
    esc[t]  = __expf(Mc + bt - mt);
  }
  {
    const int r = l >> 3, c8 = (l & 7) * 8;
    #pragma unroll
    for (int i = 0; i < 2; ++i) {
      int seg = w * 2 + i, row = seg * 8 + r;
      gload16(qkvo + (tok0 + row) * 2048 + h * 64 + c8,          &qs[seg * 512]);
      gload16(qkvo + (tok0 + row) * 2048 + 512 + h * 64 + c8,    &ks[seg * 512]);
      gload16(vTg + ((size_t)bh * 64 + row) * Ssz + c * 64 + c8, &vTs[seg * 512]);
      gload16(CstB + cbase + seg * 512 + l * 8,                  &Cs[seg * 512]);
    }
  }
  __syncthreads();

  f32x4 aS[4];
  #pragma unroll
  for (int n = 0; n < 4; ++n) aS[n] = (f32x4){0.f, 0.f, 0.f, 0.f};
  #pragma unroll
  for (int kk = 0; kk < 2; ++kk) {
    bf16x8 af = *(const bf16x8*)&qs[(w * 16 + l15) * 64 + kk * 32 + l4 * 8];
    #pragma unroll
    for (int n = 0; n < 4; ++n) {
      bf16x8 bfr = *(const bf16x8*)&ks[(n * 16 + l15) * 64 + kk * 32 + l4 * 8];
      aS[n] = __builtin_amdgcn_mfma_f32_16x16x32_bf16(af, bfr, aS[n], 0, 0, 0);
    }
  }
  {
    int row = w * 16 + (l >> 2);
    int c0 = (l & 3) * 16;
    float e = esc[row];
    #pragma unroll
    for (int i2 = 0; i2 < 2; ++i2) {
      bf16x8 v8 = *(const bf16x8*)&qs[row * 64 + c0 + i2 * 8];
      #pragma unroll
      for (int j = 0; j < 8; ++j) v8[j] = (bf16_t)((float)v8[j] * e);
      *(bf16x8*)&qs[row * 64 + c0 + i2 * 8] = v8;
    }
  }
  float rs[4] = {0.f, 0.f, 0.f, 0.f};
  #pragma unroll
  for (int n = 0; n < 4; ++n) {
    int col = n * 16 + l15;
    float es = ssrc[col];
    #pragma unroll
    for (int j = 0; j < 4; ++j) {
      int row = w * 16 + l4 * 4 + j;
      float p = (col <= row) ? aS[n][j] * __expf(es + sdst[row]) : 0.f;
      aS[n][j] = p;
      rs[j] += p;
    }
  }
  #pragma unroll
  for (int j = 0; j < 4; ++j) {
    rs[j] += __shfl_xor(rs[j], 1, 64);
    rs[j] += __shfl_xor(rs[j], 2, 64);
    rs[j] += __shfl_xor(rs[j], 4, 64);
    rs[j] += __shfl_xor(rs[j], 8, 64);
  }
  if (l15 == 0) {
    #pragma unroll
    for (int j = 0; j < 4; ++j) den_s[w * 16 + l4 * 4 + j] = rs[j];
  }
  __syncthreads();

  #pragma unroll
  for (int n = 0; n < 4; ++n)
    #pragma unroll
    for (int j = 0; j < 4; ++j)
      ks[(w * 16 + l4 * 4 + j) * 64 + n * 16 + l15] = (bf16_t)aS[n][j];

  {
    int row = w * 16 + (l >> 2);
    int c0 = (l & 3) * 16;
    float part = 0.f;
    #pragma unroll
    for (int i2 = 0; i2 < 16; ++i2)
      part += (float)qs[row * 64 + c0 + i2] * nin[c0 + i2];
    part += __shfl_xor(part, 1, 64);
    part += __shfl_xor(part, 2, 64);
    if ((l & 3) == 0)
      den_s[row] = fmaxf(fabsf(den_s[row] + part), 1.0f);
  }
  __syncthreads();

  f32x4 aO[4];
  #pragma unroll
  for (int n = 0; n < 4; ++n) aO[n] = (f32x4){0.f, 0.f, 0.f, 0.f};
  #pragma unroll
  for (int kk = 0; kk < 2; ++kk) {
    bf16x8 afP = *(const bf16x8*)&ks[(w * 16 + l15) * 64 + kk * 32 + l4 * 8];
    bf16x8 afQ = *(const bf16x8*)&qs[(w * 16 + l15) * 64 + kk * 32 + l4 * 8];
    #pragma unroll
    for (int n = 0; n < 4; ++n) {
      bf16x8 bV = *(const bf16x8*)&vTs[(n * 16 + l15) * 64 + kk * 32 + l4 * 8];
      bf16x8 bC = *(const bf16x8*)&Cs[(n * 16 + l15) * 64 + kk * 32 + l4 * 8];
      aO[n] = __builtin_amdgcn_mfma_f32_16x16x32_bf16(afP, bV, aO[n], 0, 0, 0);
      aO[n] = __builtin_amdgcn_mfma_f32_16x16x32_bf16(afQ, bC, aO[n], 0, 0, 0);
    }
  }

  #pragma unroll
  for (int j = 0; j < 4; ++j) {
    int row = w * 16 + l4 * 4 + j;
    float rinv = 1.f / den_s[row];
    float ov[4];
    #pragma unroll
    for (int n = 0; n < 4; ++n) ov[n] = aO[n][j] * rinv;
    float s = ov[0] + ov[1] + ov[2] + ov[3];
    s += __shfl_xor(s, 1, 64); s += __shfl_xor(s, 2, 64);
    s += __shfl_xor(s, 4, 64); s += __shfl_xor(s, 8, 64);
    float mu = s * (1.f / 64.f);
    float s2 = 0.f;
    #pragma unroll
    for (int n = 0; n < 4; ++n) { float d = ov[n] - mu; s2 += d * d; }
    s2 += __shfl_xor(s2, 1, 64); s2 += __shfl_xor(s2, 2, 64);
    s2 += __shfl_xor(s2, 4, 64); s2 += __shfl_xor(s2, 8, 64);
    float rstd = rsqrtf(s2 * (1.f / 64.f) + 1e-5f);
    size_t tok = tok0 + row;
    #pragma unroll
    for (int n = 0; n < 4; ++n) {
      int colh = n * 16 + l15;
      float og = (float)qkvo[tok * 2048 + 1536 + h * 64 + colh];
      float hn = (ov[n] - mu) * rstd * mhg[h * 64 + colh];
      gated[tok * 512 + h * 64 + colh] = (bf16_t)(og * hn);
    }
  }
}

/* ---------------- launcher ---------------- */
extern "C" void kernel_launch(void* const* d_in, const int* in_sizes, int n_in,
                              void* d_out, int out_size, void* d_ws, size_t ws_size,
                              hipStream_t stream) {
  const float* x     = (const float*)d_in[0];
  const float* ln_g  = (const float*)d_in[1];
  const float* ln_b  = (const float*)d_in[2];
  const float* W_up  = (const float*)d_in[3];
  const float* W_down= (const float*)d_in[4];
  const float* Wq    = (const float*)d_in[5];
  const float* Wk    = (const float*)d_in[6];
  const float* Wv    = (const float*)d_in[7];
  const float* Wi    = (const float*)d_in[8];
  const float* bi    = (const float*)d_in[9];
  const float* Wf    = (const float*)d_in[10];
  const float* bfv   = (const float*)d_in[11];
  const float* Wo    = (const float*)d_in[12];
  const float* bo    = (const float*)d_in[13];
  const float* mh_g  = (const float*)d_in[14];
  const float* W_out = (const float*)d_in[15];

  char* ws = (char*)d_ws;
  bf16_t* hbuf   = (bf16_t*)(ws + OFF_H);
  bf16_t* wqxT   = (bf16_t*)(ws + OFF_WQX);
  bf16_t* wqcT   = (bf16_t*)(ws + OFF_WQC);
  bf16_t* wdownT = (bf16_t*)(ws + OFF_WDOWNT);
  bf16_t* wocT   = (bf16_t*)(ws + OFF_WOC);
  bf16_t* wupB   = (bf16_t*)(ws + OFF_WUPB);
  bf16_t* wuifT  = (bf16_t*)(ws + OFF_WUIF);
  float*  biasA  = (float*)(ws + OFF_BIAS);
  bf16_t* woutB  = (bf16_t*)(ws + OFF_WOUTB);
  bf16_t* qkvob  = (bf16_t*)(ws + OFF_QKVO);
  bf16_t* kTg    = (bf16_t*)(ws + OFF_KT);
  bf16_t* vTg    = (bf16_t*)(ws + OFF_VT);
  bf16_t* gbuf   = (bf16_t*)(ws + OFF_GATED);
  bf16_t* Gbuf   = (bf16_t*)(ws + OFF_G);
  float*  ifb    = (float*)(ws + OFF_IFB);
  float*  bloc   = (float*)(ws + OFF_BLOC);
  float*  Mh     = (float*)(ws + OFF_MHAT);
  float*  mst    = (float*)(ws + OFF_MST);
  float*  decays = (float*)(ws + OFF_DEC);
  float*  mendb  = (float*)(ws + OFF_MEND);
  float*  ngbuf  = (float*)(ws + OFF_NG);
  float*  nst    = (float*)(ws + OFF_NST);
  float*  wocP   = (float*)(ws + OFF_WOCP);
  float*  compP  = (float*)(ws + OFF_COMPP);
  bf16_t* CstB   = (bf16_t*)(ws + OFF_CSTB);

  prep_weights<<<6337, dim3(32, 8), 0, stream>>>(W_up, Wq, Wk, Wv, Wo, W_down, W_out,
                                                 Wi, Wf, bo, bi, bfv,
                                                 wqxT, wdownT, woutB, wupB, wuifT, biasA);
  gemm_partk2<<<576, 256, 0, stream>>>(wqxT, wupB, compP, wdownT, woutB, wocP);
  reduce2<<<1920, 256, 0, stream>>>(compP, wqcT, wocP, wocT);

  ln_kernel<<<NTOK, 256, 0, stream>>>(x, ln_g, ln_b, hbuf);
  ifproj_mfma<<<NTOK / 128, 256, 0, stream>>>(hbuf, wuifT, bi, bfv, ifb);

  /* fused qkvo' = h @ Wqc (K=768) + kv-transpose + sigmoid(o); grid 512 */
  gemm_mn<5><<<dim3(2048 / 128, NTOK / 256), 512, 0, stream>>>(hbuf, wqcT, qkvob, biasA, kTg, vTg, NTOK, 2048, Dsz);

  gates_fused<<<NBH, 256, 0, stream>>>(ifb, bloc, Mh, mst, decays, mendb);
  chunk_inc_mfma<<<NBH * NCH, 256, 0, stream>>>(kTg, vTg, ifb, bloc, mendb, Gbuf, ngbuf);
  state_scan<<<136, 256, 0, stream>>>(Gbuf, ngbuf, decays, CstB, nst);
  intra_mfma<<<NBH * NCH, 256, 0, stream>>>(qkvob, vTg, CstB, nst, ifb, bloc, Mh, mst, mh_g, gbuf);

  /* fused: out = x + gated @ (W_out @ W_down), K=512 */
  gemm_mn<3><<<dim3(Dsz / 128, NTOK / 256), 512, 0, stream>>>(gbuf, wocT, (float*)d_out, x, nullptr, nullptr, NTOK, Dsz, 512);
}